// Round 9
// baseline (305.146 us; speedup 1.0000x reference)
//
#include <hip/hip_runtime.h>
#include <hip/hip_bf16.h>

// ---------------------------------------------------------------------------
// DiffusionModule: AttentionPairBias + ConditionedFeedForward (AF3-style)
// B=1, N=1024, DS=768, DP=128, H=16, DH=48, DFF=1536. f32 in/out, bf16 MFMA.
// R9: pair stream decoupled into a low-VGPR high-occupancy kernel (fused with
// prep's cheap transpose/LN paths); GEMMs standalone.
// ---------------------------------------------------------------------------

typedef __attribute__((ext_vector_type(8))) short bf16x8;
typedef __attribute__((ext_vector_type(4))) float f32x4;
typedef __attribute__((ext_vector_type(4))) unsigned short us4;

#define DEVFN static __device__ __forceinline__

DEVFN float bf2f(unsigned short u){
  union { unsigned int u; float f; } v; v.u = ((unsigned int)u) << 16; return v.f;
}
DEVFN unsigned short f2bf(float f){
  union { float f; unsigned int u; } v; v.f = f;
  unsigned int r = v.u + 0x7fffu + ((v.u >> 16) & 1u);
  return (unsigned short)(r >> 16);
}
DEVFN unsigned short f2bf_trunc(float f){
  union { float f; unsigned int u; } v; v.f = f;
  return (unsigned short)(v.u >> 16);
}
DEVFN float sigf(float x){ return 1.f / (1.f + __expf(-x)); }

DEVFN void gload16(const void* g, void* l){
  __builtin_amdgcn_global_load_lds(
      (const __attribute__((address_space(1))) void*)g,
      (__attribute__((address_space(3))) void*)l, 16, 0, 0);
}

// ---------------- workspace layout (bytes) ----------------
#define OFF_SN    0x0000000ULL
#define OFF_SC    0x0180000ULL
#define OFF_XA    0x0300000ULL
#define OFF_W1    0x0600000ULL
#define OFF_W2    0x0A80000ULL
#define OFF_W3    0x0CC0000ULL
#define OFF_W4    0x1140000ULL
#define OFF_W5    0x15C0000ULL
#define OFF_W6    0x1800000ULL
#define OFF_BIAS1 0x1920000ULL
#define OFF_BIASG 0x1923000ULL
#define OFF_BIASQ 0x1924800ULL
#define OFF_G1    0x1930000ULL
#define OFF_GATES 0x2530000ULL
#define OFF_A     0x2B30000ULL
#define OFF_F     0x2CB0000ULL
#define OFF_QH    0x2E30000ULL
#define OFF_KH    0x2FB0000ULL
#define OFF_GH    0x3130000ULL
#define OFF_VT    0x3430000ULL
#define OFF_HH    0x4030000ULL
#define OFF_GO    0x4330000ULL
#define OFF_PB    0x47B0000ULL

struct WJobs {
  const float* src[14];
  unsigned long long dst[14];
  int K[14];
  int N[14];
  int rowmul[14];
  int rowoff[14];
};

// ---------------- pair-bias block (256 (i,j) rows via MFMA, low-VGPR) ------
DEVFN void pair_block(int pbid, const float* __restrict__ pair,
                      const float* __restrict__ wb,
                      unsigned short* __restrict__ pb, int tid){
  const int l = tid & 63, w = tid >> 6, l15 = l & 15, l4 = l >> 4;
  bf16x8 wbf[4];
  #pragma unroll
  for(int c=0;c<4;c++){
    bf16x8 t;
    #pragma unroll
    for(int e=0;e<8;e++) t[e] = (short)f2bf(wb[(c*32 + l4*8 + e)*16 + l15]);
    wbf[c] = t;
  }
  #pragma unroll
  for(int q=0;q<4;q++){
    const long long row0 = (((long long)pbid) * 16 + q*4 + w) << 4;
    const float* pr = pair + ((row0 + l15) << 7);
    float vals[32];
    #pragma unroll
    for(int c=0;c<4;c++){
      float4 v0 = *(const float4*)(pr + c*32 + l4*8);
      float4 v1 = *(const float4*)(pr + c*32 + l4*8 + 4);
      vals[c*8+0]=v0.x; vals[c*8+1]=v0.y; vals[c*8+2]=v0.z; vals[c*8+3]=v0.w;
      vals[c*8+4]=v1.x; vals[c*8+5]=v1.y; vals[c*8+6]=v1.z; vals[c*8+7]=v1.w;
    }
    float s=0.f, s2=0.f;
    #pragma unroll
    for(int e=0;e<32;e++){ s += vals[e]; s2 += vals[e]*vals[e]; }
    s += __shfl_xor(s, 16); s2 += __shfl_xor(s2, 16);
    s += __shfl_xor(s, 32); s2 += __shfl_xor(s2, 32);
    const float m = s * (1.f/128.f);
    const float rs = rsqrtf(s2*(1.f/128.f) - m*m + 1e-5f);
    f32x4 acc = {0.f,0.f,0.f,0.f};
    #pragma unroll
    for(int c=0;c<4;c++){
      bf16x8 af;
      #pragma unroll
      for(int e=0;e<8;e++) af[e] = (short)f2bf_trunc((vals[c*8+e] - m) * rs);
      acc = __builtin_amdgcn_mfma_f32_16x16x32_bf16(af, wbf[c], acc, 0,0,0);
    }
    us4 o;
    #pragma unroll
    for(int r=0;r<4;r++) o[r] = f2bf(acc[r]);
    *(us4*)&pb[((long long)l15 << 20) + row0 + l4*4] = o;
  }
}

// ---------------- stream kernel: pair (4096) + prep (10828), high occupancy
// bid < 4096: pair tile. Else prep: [0,9792) transpose, [9792,10816) LN,
// [10816,10828) bias. __launch_bounds__(256,6): VGPR<=85 -> 24 waves/CU.
__global__ __launch_bounds__(256, 6) void stream_kernel(WJobs jobs, char* ws,
    const float* __restrict__ pair, const float* __restrict__ wb,
    unsigned short* __restrict__ pb,
    const float* __restrict__ x, const float* __restrict__ sc,
    unsigned short* __restrict__ sn_bf, unsigned short* __restrict__ sc_bf,
    float* __restrict__ xa,
    const float* agb, const float* bq, const float* gtb, const float* fgtb,
    const float* fgb, float* bias1, float* biasg, float* biasq){
  __shared__ __align__(16) float smem[32*33 + 16];
  const int bid = blockIdx.x;
  const int tid = threadIdx.x;
  if(bid < 4096){
    pair_block(bid, pair, wb, pb, tid);
    return;
  }
  const int it = bid - 4096;
  if(it < 9792){
    // ---- transpose+cast tile ----
    int t = it, z = 0;
    while(true){
      int nt = (jobs.N[z] >> 5) * (jobs.K[z] >> 5);
      if(t < nt) break;
      t -= nt; z++;
    }
    const int nx = jobs.N[z] >> 5;
    const int n0 = (t % nx) << 5, k0 = (t / nx) << 5;
    const int K = jobs.K[z], N = jobs.N[z];
    float (*tt)[33] = (float(*)[33])smem;
    const int tx = tid & 31, ty = tid >> 5;
    const float* src = jobs.src[z];
    #pragma unroll
    for(int i=0;i<4;i++)
      tt[ty + i*8][tx] = src[(long long)(k0 + ty + i*8) * N + n0 + tx];
    __syncthreads();
    unsigned short* dst = (unsigned short*)(ws + jobs.dst[z]);
    const int rm = jobs.rowmul[z], ro = jobs.rowoff[z];
    #pragma unroll
    for(int i=0;i<4;i++)
      dst[(long long)((n0 + ty + i*8)*rm + ro) * K + k0 + tx] = f2bf(tt[tx][ty + i*8]);
    return;
  }
  if(it >= 10816){
    int t = (it - 10816) * 256 + tid;
    float v = 0.f;
    if(t < 768) v = agb[t];
    else if(t >= 1536 && t < 2304) v = fgb[t - 1536];
    bias1[t] = v;
    biasq[t] = (t < 768) ? bq[t] : 0.f;
    if(t < 1536) biasg[t] = (t < 768) ? gtb[t] : fgtb[t - 768];
    return;
  }
  // ---- LN row ----
  const int row = it - 9792;
  const float* xr = x + (long long)row * 768;
  const float* sr = sc + (long long)row * 768;
  float xs[3], ss[3];
  float s0=0.f, s1=0.f, s2=0.f, s3=0.f;
  #pragma unroll
  for(int i=0;i<3;i++){
    float xv = xr[tid + i*256], sv = sr[tid + i*256];
    xs[i]=xv; ss[i]=sv;
    s0 += xv; s1 += xv*xv; s2 += sv; s3 += sv*sv;
  }
  #pragma unroll
  for(int o=32;o;o>>=1){
    s0 += __shfl_xor(s0,o); s1 += __shfl_xor(s1,o);
    s2 += __shfl_xor(s2,o); s3 += __shfl_xor(s3,o);
  }
  float (*red)[4] = (float(*)[4])smem;
  const int w = tid >> 6;
  if((tid & 63) == 0){ red[0][w]=s0; red[1][w]=s1; red[2][w]=s2; red[3][w]=s3; }
  __syncthreads();
  float tx0 = red[0][0]+red[0][1]+red[0][2]+red[0][3];
  float tx1 = red[1][0]+red[1][1]+red[1][2]+red[1][3];
  float ts0 = red[2][0]+red[2][1]+red[2][2]+red[2][3];
  float ts1 = red[3][0]+red[3][1]+red[3][2]+red[3][3];
  const float inv = 1.f/768.f;
  float mx = tx0*inv, vx = tx1*inv - mx*mx;
  float ms = ts0*inv, vs = ts1*inv - ms*ms;
  float rsx = rsqrtf(vx + 1e-5f), rss = rsqrtf(vs + 1e-5f);
  #pragma unroll
  for(int i=0;i<3;i++){
    int c = tid + i*256;
    xa[(long long)row*768 + c]    = (xs[i]-mx)*rsx;
    sn_bf[(long long)row*768 + c] = f2bf((ss[i]-ms)*rss);
    sc_bf[(long long)row*768 + c] = f2bf(ss[i]);
  }
}

// ---------------- shared GEMM tile body (128x128, BK=32, gload_lds) --------
DEVFN void gemm_tile_f32(const unsigned short* __restrict__ A,
                         const unsigned short* __restrict__ Bt,
                         int N, int K, int m0, int n0,
                         const float* __restrict__ bias,
                         float* __restrict__ Cf, int epi,
                         unsigned short* sA, unsigned short* sB, int tid){
  const int w = tid >> 6, l = tid & 63, l15 = l & 15, l4 = l >> 4;
  const int wm = w >> 1, wn = w & 1;
  f32x4 zf = {0.f,0.f,0.f,0.f};
  f32x4 acc[4][4];
  #pragma unroll
  for(int m=0;m<4;m++)
    #pragma unroll
    for(int n=0;n<4;n++) acc[m][n] = zf;

  const int srow = w*16 + (l >> 2);
  const int scol = (l & 3) * 8;
  const unsigned short* gA = A  + (long long)(m0 + srow) * K + scol;
  const unsigned short* gB = Bt + (long long)(n0 + srow) * K + scol;
  unsigned short* lA0 = &sA[(w*16)*32];
  unsigned short* lA1 = &sA[(64 + w*16)*32];
  unsigned short* lB0 = &sB[(w*16)*32];
  unsigned short* lB1 = &sB[(64 + w*16)*32];
  const long long half = (long long)64 * K;

  for(int k0 = 0; k0 < K; k0 += 32){
    gload16(gA + k0, lA0);
    gload16(gA + half + k0, lA1);
    gload16(gB + k0, lB0);
    gload16(gB + half + k0, lB1);
    __syncthreads();
    bf16x8 af[4], bg[4];
    #pragma unroll
    for(int m=0;m<4;m++) af[m] = *(const bf16x8*)&sA[(wm*64 + m*16 + l15)*32 + l4*8];
    #pragma unroll
    for(int n=0;n<4;n++) bg[n] = *(const bf16x8*)&sB[(wn*64 + n*16 + l15)*32 + l4*8];
    #pragma unroll
    for(int m=0;m<4;m++)
      #pragma unroll
      for(int n=0;n<4;n++)
        acc[m][n] = __builtin_amdgcn_mfma_f32_16x16x32_bf16(af[m], bg[n], acc[m][n], 0, 0, 0);
    __syncthreads();
  }
  #pragma unroll
  for(int m=0;m<4;m++){
    #pragma unroll
    for(int n=0;n<4;n++){
      #pragma unroll
      for(int r=0;r<4;r++){
        const int i = m0 + wm*64 + m*16 + l4*4 + r;
        const int c = n0 + wn*64 + n*16 + l15;
        float v = acc[m][n][r] + bias[c];
        Cf[(long long)i*N + c] = epi ? sigf(v) : v;
      }
    }
  }
}

// ---------------- gemmA: G1 (192 tiles) + gates (96 tiles) ----------------
__global__ __launch_bounds__(256) void gemmA_kernel(
    const unsigned short* __restrict__ SN, const unsigned short* __restrict__ W1,
    const float* __restrict__ B1, float* __restrict__ G1,
    const unsigned short* __restrict__ SC, const unsigned short* __restrict__ W2,
    const float* __restrict__ BG, float* __restrict__ GT){
  __shared__ __align__(16) unsigned short sA[128*32];
  __shared__ __align__(16) unsigned short sB[128*32];
  const int bid = blockIdx.x;
  const int tid = threadIdx.x;
  if(bid < 192){
    gemm_tile_f32(SN, W1, 3072, 768, (bid & 7)*128, (bid >> 3)*128, B1, G1, 0, sA, sB, tid);
  } else {
    const int t = bid - 192;
    gemm_tile_f32(SC, W2, 1536, 768, (t & 7)*128, (t >> 3)*128, BG, GT, 1, sA, sB, tid);
  }
}

// ---------------- elementwise: adaLN combine + out=x init ----------------
__global__ __launch_bounds__(256) void ew1_kernel(const float* __restrict__ g1,
    const float* __restrict__ xa, unsigned short* __restrict__ a_bf,
    unsigned short* __restrict__ f_bf, const float* __restrict__ x,
    float* __restrict__ out){
  const int i = blockIdx.x;
  const int c = blockIdx.y * 256 + threadIdx.x;
  const float* row = g1 + (long long)i * 3072;
  float xv = xa[(long long)i*768 + c];
  a_bf[(long long)i*768 + c] = f2bf(sigf(row[c])      * xv + row[768 + c]);
  f_bf[(long long)i*768 + c] = f2bf(sigf(row[1536+c]) * xv + row[2304 + c]);
  out[(long long)i*768 + c] = x[(long long)i*768 + c];
}

// ---------------- gemmB: QKVG (head-major out) + HH SwiGLU ----------------
__global__ __launch_bounds__(256) void gemmB_kernel(
    const unsigned short* __restrict__ A_, const unsigned short* __restrict__ W3,
    const float* __restrict__ BQ,
    unsigned short* __restrict__ QH, unsigned short* __restrict__ KH,
    unsigned short* __restrict__ GH, unsigned short* __restrict__ VT,
    const unsigned short* __restrict__ F_, const unsigned short* __restrict__ W4,
    unsigned short* __restrict__ HH){
  __shared__ __align__(16) unsigned short sA[128*32];
  __shared__ __align__(16) unsigned short sB[128*32];
  const int bid = blockIdx.x;
  const int tid = threadIdx.x;
  const bool isq = bid < 192;
  const int t = isq ? bid : bid - 192;
  const int m0 = (t & 7) * 128, n0 = (t >> 3) * 128;
  const unsigned short* A  = isq ? A_ : F_;
  const unsigned short* Bt = isq ? W3 : W4;
  const int K = 768;

  const int w = tid >> 6, l = tid & 63, l15 = l & 15, l4 = l >> 4;
  const int wm = w >> 1, wn = w & 1;
  f32x4 zf = {0.f,0.f,0.f,0.f};
  f32x4 acc[4][4];
  #pragma unroll
  for(int m=0;m<4;m++)
    #pragma unroll
    for(int n=0;n<4;n++) acc[m][n] = zf;

  const int srow = w*16 + (l >> 2);
  const int scol = (l & 3) * 8;
  const unsigned short* gA = A  + (long long)(m0 + srow) * K + scol;
  const unsigned short* gB = Bt + (long long)(n0 + srow) * K + scol;
  unsigned short* lA0 = &sA[(w*16)*32];
  unsigned short* lA1 = &sA[(64 + w*16)*32];
  unsigned short* lB0 = &sB[(w*16)*32];
  unsigned short* lB1 = &sB[(64 + w*16)*32];
  const long long half = (long long)64 * K;

  for(int k0 = 0; k0 < K; k0 += 32){
    gload16(gA + k0, lA0);
    gload16(gA + half + k0, lA1);
    gload16(gB + k0, lB0);
    gload16(gB + half + k0, lB1);
    __syncthreads();
    bf16x8 af[4], bg[4];
    #pragma unroll
    for(int m=0;m<4;m++) af[m] = *(const bf16x8*)&sA[(wm*64 + m*16 + l15)*32 + l4*8];
    #pragma unroll
    for(int n=0;n<4;n++) bg[n] = *(const bf16x8*)&sB[(wn*64 + n*16 + l15)*32 + l4*8];
    #pragma unroll
    for(int m=0;m<4;m++)
      #pragma unroll
      for(int n=0;n<4;n++)
        acc[m][n] = __builtin_amdgcn_mfma_f32_16x16x32_bf16(af[m], bg[n], acc[m][n], 0, 0, 0);
    __syncthreads();
  }
  if(isq){
    #pragma unroll
    for(int m=0;m<4;m++){
      #pragma unroll
      for(int n=0;n<4;n++){
        const int c = n0 + wn*64 + n*16 + l15;
        const int ibase = m0 + wm*64 + m*16 + l4*4;
        const int which = c / 768;           // 0=q 1=k 2=v 3=g
        const int h = (c % 768) / 48, d = c % 48;
        unsigned short vb[4];
        #pragma unroll
        for(int r=0;r<4;r++) vb[r] = f2bf(acc[m][n][r] + BQ[c]);
        if(which == 2){
          us4 o; o.x=vb[0]; o.y=vb[1]; o.z=vb[2]; o.w=vb[3];
          *(us4*)&VT[((long long)(c - 1536) << 10) + ibase] = o;
        } else {
          unsigned short* dst = (which == 0) ? QH : (which == 1) ? KH : GH;
          #pragma unroll
          for(int r=0;r<4;r++)
            dst[((long long)((h << 10) + ibase + r))*48 + d] = vb[r];
        }
      }
    }
  } else {
    #pragma unroll
    for(int m=0;m<4;m++){
      #pragma unroll
      for(int n=0;n<4;n++){
        #pragma unroll
        for(int r=0;r<4;r++){
          const int i = m0 + wm*64 + m*16 + l4*4 + r;
          const int c = n0 + wn*64 + n*16 + l15;
          float v = acc[m][n][r];
          float partner = __shfl_xor(v, 1);
          if((c & 1) == 0)
            HH[(long long)i*1536 + (c>>1)] = f2bf(v * sigf(v) * partner);
        }
      }
    }
  }
}

// ---------------- attention: per (head, 16-row tile), head-major layouts ---
__global__ __launch_bounds__(256) void attn_kernel(
    const unsigned short* __restrict__ QH, const unsigned short* __restrict__ KH,
    const unsigned short* __restrict__ GH,
    const unsigned short* __restrict__ pbias,
    const unsigned short* __restrict__ VT,
    unsigned short* __restrict__ go){
  const int h  = blockIdx.x >> 6;
  const int i0 = (blockIdx.x & 63) << 4;
  const int tid = threadIdx.x;
  const int w = tid >> 6, l = tid & 63, l15 = l & 15, l4 = l >> 4;

  __shared__ unsigned short sP[16][1032];
  __shared__ float sRedM[16][4];
  __shared__ float sRedS[16][4];
  __shared__ float sO[4][16][48];

  f32x4 zf = {0.f,0.f,0.f,0.f};
  bf16x8 zero8 = {0,0,0,0,0,0,0,0};

  const unsigned short* pbh = pbias + ((long long)h << 20) + ((long long)i0 << 10);
  #pragma unroll
  for(int it=0; it<8; it++){
    const int idx = it*2048 + tid*8;
    const int r = idx >> 10, c = idx & 1023;
    *(bf16x8*)&sP[r][c] = *(const bf16x8*)&pbh[((long long)r << 10) + c];
  }

  // ---- QK^T ----
  f32x4 accs[16];
  #pragma unroll
  for(int f=0;f<16;f++) accs[f] = zf;
  bf16x8 aq0, aq1;
  {
    const unsigned short* qp = QH + (long long)((h << 10) + i0 + l15)*48;
    aq0 = *(const bf16x8*)(qp + l4*8);
    aq1 = *(const bf16x8*)(qp + 32 + l4*8);
  }
  const int jbase = w * 256;
  #pragma unroll
  for(int f=0; f<16; f++){
    const int j = jbase + f*16 + l15;
    const unsigned short* kp = KH + (long long)((h << 10) + j)*48;
    bf16x8 bk0 = *(const bf16x8*)(kp + l4*8);
    bf16x8 bk1 = *(const bf16x8*)(kp + 32 + l4*8);
    if(l4 >= 2) bk1 = zero8;
    accs[f] = __builtin_amdgcn_mfma_f32_16x16x32_bf16(aq0, bk0, accs[f], 0,0,0);
    accs[f] = __builtin_amdgcn_mfma_f32_16x16x32_bf16(aq1, bk1, accs[f], 0,0,0);
  }
  __syncthreads();   // sP bias staged

  const float scale = 0.14433756729740643f;  // 1/sqrt(48)
  #pragma unroll
  for(int f=0;f<16;f++){
    #pragma unroll
    for(int r=0;r<4;r++)
      accs[f][r] = accs[f][r]*scale + bf2f(sP[l4*4 + r][jbase + f*16 + l15]);
  }
  // ---- softmax (unnormalized) ----
  float pm[4];
  #pragma unroll
  for(int r=0;r<4;r++){
    float m = accs[0][r];
    #pragma unroll
    for(int f=1;f<16;f++) m = fmaxf(m, accs[f][r]);
    #pragma unroll
    for(int o=1;o<16;o<<=1) m = fmaxf(m, __shfl_xor(m, o));
    pm[r] = m;
  }
  if(l15 == 0){
    #pragma unroll
    for(int r=0;r<4;r++) sRedM[l4*4 + r][w] = pm[r];
  }
  __syncthreads();
  float rowm[4];
  #pragma unroll
  for(int r=0;r<4;r++){
    const int i = l4*4 + r;
    rowm[r] = fmaxf(fmaxf(sRedM[i][0], sRedM[i][1]), fmaxf(sRedM[i][2], sRedM[i][3]));
  }
  float psum[4] = {0.f,0.f,0.f,0.f};
  #pragma unroll
  for(int f=0;f<16;f++)
    #pragma unroll
    for(int r=0;r<4;r++){
      float p = __expf(accs[f][r] - rowm[r]);
      accs[f][r] = p;
      psum[r] += p;
    }
  #pragma unroll
  for(int r=0;r<4;r++)
    #pragma unroll
    for(int o=1;o<16;o<<=1) psum[r] += __shfl_xor(psum[r], o);
  if(l15 == 0){
    #pragma unroll
    for(int r=0;r<4;r++) sRedS[l4*4 + r][w] = psum[r];
  }
  #pragma unroll
  for(int f=0;f<16;f++)
    #pragma unroll
    for(int r=0;r<4;r++)
      sP[l4*4 + r][jbase + f*16 + l15] = f2bf(accs[f][r]);

  // ---- PV: B-frags straight from global VT (L2-hot) ----
  f32x4 acco[3];
  #pragma unroll
  for(int n=0;n<3;n++) acco[n] = zf;
  const unsigned short* vth = VT + ((long long)(h*48) << 10);
  #pragma unroll
  for(int c=0; c<4; c++){
    const int jb = jbase + c*64;
    #pragma unroll
    for(int kk=0; kk<2; kk++){
      bf16x8 pa = *(const bf16x8*)&sP[l15][jb + kk*32 + l4*8];
      #pragma unroll
      for(int n=0;n<3;n++){
        bf16x8 bv = *(const bf16x8*)&vth[((long long)(n*16 + l15) << 10) + jb + kk*32 + l4*8];
        acco[n] = __builtin_amdgcn_mfma_f32_16x16x32_bf16(pa, bv, acco[n], 0,0,0);
      }
    }
  }
  #pragma unroll
  for(int n=0;n<3;n++)
    #pragma unroll
    for(int r=0;r<4;r++)
      sO[w][l4*4 + r][n*16 + l15] = acco[n][r];
  __syncthreads();
  for(int t = tid; t < 768; t += 256){
    const int i = t / 48, d = t % 48;
    float o = sO[0][i][d] + sO[1][i][d] + sO[2][i][d] + sO[3][i][d];
    float lsum = sRedS[i][0] + sRedS[i][1] + sRedS[i][2] + sRedS[i][3];
    float gv = bf2f(GH[(long long)((h << 10) + i0 + i)*48 + d]);
    go[(long long)(i0 + i)*768 + h*48 + d] = f2bf(sigf(gv) * (o / lsum));
  }
}

// ---------------- final: out += gA*(GO@W6) + gF*(HH@W5), split-K ----------
__global__ __launch_bounds__(256) void final_kernel(
    const unsigned short* __restrict__ GO, const unsigned short* __restrict__ W6t,
    const unsigned short* __restrict__ HH, const unsigned short* __restrict__ W5t,
    const float* __restrict__ gates, float* __restrict__ out){
  __shared__ __align__(16) unsigned short sA[128*32];
  __shared__ __align__(16) unsigned short sB[128*32];
  const int m0 = blockIdx.x * 128, n0 = blockIdx.y * 128;
  const int z = blockIdx.z;
  const bool pA = z < 4;
  const unsigned short* A  = pA ? GO  : HH;
  const unsigned short* Bt = pA ? W6t : W5t;
  const int K    = pA ? 768 : 1536;
  const int kbeg = pA ? z*192 : (z-4)*384;
  const int kend = pA ? kbeg + 192 : kbeg + 384;
  const int goff = pA ? 0 : 768;
  const int tid = threadIdx.x;
  const int w = tid >> 6, l = tid & 63, l15 = l & 15, l4 = l >> 4;
  const int wm = w >> 1, wn = w & 1;
  f32x4 zf = {0.f,0.f,0.f,0.f};
  f32x4 acc[4][4];
  #pragma unroll
  for(int m=0;m<4;m++)
    #pragma unroll
    for(int n=0;n<4;n++) acc[m][n] = zf;

  const int srow = w*16 + (l >> 2);
  const int scol = (l & 3) * 8;
  const unsigned short* gA = A  + (long long)(m0 + srow) * K + scol;
  const unsigned short* gB = Bt + (long long)(n0 + srow) * K + scol;
  unsigned short* lA0 = &sA[(w*16)*32];
  unsigned short* lA1 = &sA[(64 + w*16)*32];
  unsigned short* lB0 = &sB[(w*16)*32];
  unsigned short* lB1 = &sB[(64 + w*16)*32];
  const long long half = (long long)64 * K;

  for(int k0 = kbeg; k0 < kend; k0 += 32){
    gload16(gA + k0, lA0);
    gload16(gA + half + k0, lA1);
    gload16(gB + k0, lB0);
    gload16(gB + half + k0, lB1);
    __syncthreads();
    bf16x8 af[4], bg[4];
    #pragma unroll
    for(int m=0;m<4;m++) af[m] = *(const bf16x8*)&sA[(wm*64 + m*16 + l15)*32 + l4*8];
    #pragma unroll
    for(int n=0;n<4;n++) bg[n] = *(const bf16x8*)&sB[(wn*64 + n*16 + l15)*32 + l4*8];
    #pragma unroll
    for(int m=0;m<4;m++)
      #pragma unroll
      for(int n=0;n<4;n++)
        acc[m][n] = __builtin_amdgcn_mfma_f32_16x16x32_bf16(af[m], bg[n], acc[m][n], 0, 0, 0);
    __syncthreads();
  }
  #pragma unroll
  for(int m=0;m<4;m++){
    #pragma unroll
    for(int n=0;n<4;n++){
      #pragma unroll
      for(int r=0;r<4;r++){
        const int i = m0 + wm*64 + m*16 + l4*4 + r;
        const int c = n0 + wn*64 + n*16 + l15;
        float v = gates[(long long)i*1536 + goff + c] * acc[m][n][r];
        __hip_atomic_fetch_add(&out[(long long)i*768 + c], v,
                               __ATOMIC_RELAXED, __HIP_MEMORY_SCOPE_AGENT);
      }
    }
  }
}

// ---------------------------------------------------------------------------
extern "C" void kernel_launch(void* const* d_in, const int* in_sizes, int n_in,
                              void* d_out, int out_size, void* d_ws, size_t ws_size,
                              hipStream_t stream){
  (void)in_sizes; (void)n_in; (void)out_size; (void)ws_size;
  const float* x    = (const float*)d_in[0];
  const float* sc   = (const float*)d_in[1];
  const float* pair = (const float*)d_in[2];
  const float* agw  = (const float*)d_in[3];
  const float* agb  = (const float*)d_in[4];
  const float* abw  = (const float*)d_in[5];
  const float* wq   = (const float*)d_in[6];
  const float* bq   = (const float*)d_in[7];
  const float* wk   = (const float*)d_in[8];
  const float* wv   = (const float*)d_in[9];
  const float* wb   = (const float*)d_in[10];
  const float* wg   = (const float*)d_in[11];
  const float* wo   = (const float*)d_in[12];
  const float* gtw  = (const float*)d_in[13];
  const float* gtb  = (const float*)d_in[14];
  const float* fgw  = (const float*)d_in[15];
  const float* fgb  = (const float*)d_in[16];
  const float* fbw  = (const float*)d_in[17];
  const float* fw1  = (const float*)d_in[18];
  const float* fw2  = (const float*)d_in[19];
  const float* fw3  = (const float*)d_in[20];
  const float* fgtw = (const float*)d_in[21];
  const float* fgtb = (const float*)d_in[22];
  float* out = (float*)d_out;
  char* ws = (char*)d_ws;

  unsigned short* SN   = (unsigned short*)(ws + OFF_SN);
  unsigned short* SC   = (unsigned short*)(ws + OFF_SC);
  float*          XA   = (float*)(ws + OFF_XA);
  unsigned short* W1   = (unsigned short*)(ws + OFF_W1);
  unsigned short* W2   = (unsigned short*)(ws + OFF_W2);
  unsigned short* W3   = (unsigned short*)(ws + OFF_W3);
  unsigned short* W4   = (unsigned short*)(ws + OFF_W4);
  unsigned short* W5   = (unsigned short*)(ws + OFF_W5);
  unsigned short* W6   = (unsigned short*)(ws + OFF_W6);
  float*          B1   = (float*)(ws + OFF_BIAS1);
  float*          BG   = (float*)(ws + OFF_BIASG);
  float*          BQ   = (float*)(ws + OFF_BIASQ);
  float*          G1   = (float*)(ws + OFF_G1);
  float*          GT   = (float*)(ws + OFF_GATES);
  unsigned short* A_   = (unsigned short*)(ws + OFF_A);
  unsigned short* F_   = (unsigned short*)(ws + OFF_F);
  unsigned short* QH   = (unsigned short*)(ws + OFF_QH);
  unsigned short* KH   = (unsigned short*)(ws + OFF_KH);
  unsigned short* GH   = (unsigned short*)(ws + OFF_GH);
  unsigned short* VT   = (unsigned short*)(ws + OFF_VT);
  unsigned short* HH   = (unsigned short*)(ws + OFF_HH);
  unsigned short* GO   = (unsigned short*)(ws + OFF_GO);
  unsigned short* PB   = (unsigned short*)(ws + OFF_PB);

  WJobs jobs;
  int ji = 0;
  auto setj = [&](const float* s, unsigned long long off, int K, int N,
                  int rm = 1, int ro = 0){
    jobs.src[ji]=s; jobs.dst[ji]=off; jobs.K[ji]=K; jobs.N[ji]=N;
    jobs.rowmul[ji]=rm; jobs.rowoff[ji]=ro; ji++;
  };
  const unsigned long long W768 = 768ULL*768ULL*2ULL;
  setj(agw,  OFF_W1 + 0*W768, 768, 768);
  setj(abw,  OFF_W1 + 1*W768, 768, 768);
  setj(fgw,  OFF_W1 + 2*W768, 768, 768);
  setj(fbw,  OFF_W1 + 3*W768, 768, 768);
  setj(gtw,  OFF_W2 + 0*W768, 768, 768);
  setj(fgtw, OFF_W2 + 1*W768, 768, 768);
  setj(wq,   OFF_W3 + 0*W768, 768, 768);
  setj(wk,   OFF_W3 + 1*W768, 768, 768);
  setj(wv,   OFF_W3 + 2*W768, 768, 768);
  setj(wg,   OFF_W3 + 3*W768, 768, 768);
  setj(fw1,  OFF_W4, 768, 1536, 2, 0);   // interleaved: row 2c   = w1 col c
  setj(fw2,  OFF_W4, 768, 1536, 2, 1);   //              row 2c+1 = w2 col c
  setj(fw3,  OFF_W5, 1536, 768);
  setj(wo,   OFF_W6, 768, 768);

  // stream: pair (4096, high-occupancy) + prep (10828) fused
  stream_kernel<<<14924, 256, 0, stream>>>(jobs, ws, pair, wb, PB,
      x, sc, SN, SC, XA, agb, bq, gtb, fgtb, fgb, B1, BG, BQ);
  // G1 + gates GEMMs
  gemmA_kernel<<<288, 256, 0, stream>>>(SN, W1, B1, G1, SC, W2, BG, GT);
  // adaLN combine -> a, f (bf16); also out = x
  ew1_kernel<<<dim3(1024,3), 256, 0, stream>>>(G1, XA, A_, F_, x, out);
  // QKVG(head-major)+HH GEMMs
  gemmB_kernel<<<384, 256, 0, stream>>>(A_, W3, BQ, QH, KH, GH, VT, F_, W4, HH);
  // attention -> go = sigmoid(g)*o (bf16)
  attn_kernel<<<1024, 256, 0, stream>>>(QH, KH, GH, PB, VT, GO);
  // out += gateA*(GO@wo) + gateF*(HH@w3)   (split-K atomics)
  final_kernel<<<dim3(8,6,8), 256, 0, stream>>>(GO, W6, HH, W5, GT, out);
}

// Round 10
// 286.246 us; speedup vs baseline: 1.0660x; 1.0660x over previous
//
#include <hip/hip_runtime.h>
#include <hip/hip_bf16.h>

// ---------------------------------------------------------------------------
// DiffusionModule: AttentionPairBias + ConditionedFeedForward (AF3-style)
// B=1, N=1024, DS=768, DP=128, H=16, DH=48, DFF=1536. f32 in/out, bf16 MFMA.
// R10 = R6 + coalesced pair stream: global_load_lds staging, source-side XOR
// swizzle (rule #21: linear LDS dest + inv-swz source + swz read).
// ---------------------------------------------------------------------------

typedef __attribute__((ext_vector_type(8))) short bf16x8;
typedef __attribute__((ext_vector_type(4))) float f32x4;
typedef __attribute__((ext_vector_type(4))) unsigned short us4;

#define DEVFN static __device__ __forceinline__

DEVFN float bf2f(unsigned short u){
  union { unsigned int u; float f; } v; v.u = ((unsigned int)u) << 16; return v.f;
}
DEVFN unsigned short f2bf(float f){
  union { float f; unsigned int u; } v; v.f = f;
  unsigned int r = v.u + 0x7fffu + ((v.u >> 16) & 1u);
  return (unsigned short)(r >> 16);
}
DEVFN unsigned short f2bf_trunc(float f){
  union { float f; unsigned int u; } v; v.f = f;
  return (unsigned short)(v.u >> 16);
}
DEVFN float sigf(float x){ return 1.f / (1.f + __expf(-x)); }

DEVFN void gload16(const void* g, void* l){
  __builtin_amdgcn_global_load_lds(
      (const __attribute__((address_space(1))) void*)g,
      (__attribute__((address_space(3))) void*)l, 16, 0, 0);
}

// ---------------- workspace layout (bytes) ----------------
#define OFF_SN    0x0000000ULL
#define OFF_SC    0x0180000ULL
#define OFF_XA    0x0300000ULL
#define OFF_W1    0x0600000ULL
#define OFF_W2    0x0A80000ULL
#define OFF_W3    0x0CC0000ULL
#define OFF_W4    0x1140000ULL
#define OFF_W5    0x15C0000ULL
#define OFF_W6    0x1800000ULL
#define OFF_BIAS1 0x1920000ULL
#define OFF_BIASG 0x1923000ULL
#define OFF_BIASQ 0x1924800ULL
#define OFF_G1    0x1930000ULL
#define OFF_GATES 0x2530000ULL
#define OFF_A     0x2B30000ULL
#define OFF_F     0x2CB0000ULL
#define OFF_QH    0x2E30000ULL
#define OFF_KH    0x2FB0000ULL
#define OFF_GH    0x3130000ULL
#define OFF_VT    0x3430000ULL
#define OFF_HH    0x4030000ULL
#define OFF_GO    0x4330000ULL
#define OFF_PB    0x47B0000ULL

struct WJobs {
  const float* src[14];
  unsigned long long dst[14];
  int K[14];
  int N[14];
  int rowmul[14];
  int rowoff[14];
};

// ---------------- prep: weight transpose tiles + LN rows + bias build ------
__global__ __launch_bounds__(256) void prep_kernel(WJobs jobs, char* ws,
    const float* __restrict__ x, const float* __restrict__ sc,
    unsigned short* __restrict__ sn_bf, unsigned short* __restrict__ sc_bf,
    float* __restrict__ xa,
    const float* agb, const float* bq, const float* gtb, const float* fgtb,
    const float* fgb, float* bias1, float* biasg, float* biasq){
  const int bid = blockIdx.x;
  const int tid = threadIdx.x;
  if(bid < 9792){
    int t = bid, z = 0;
    while(true){
      int nt = (jobs.N[z] >> 5) * (jobs.K[z] >> 5);
      if(t < nt) break;
      t -= nt; z++;
    }
    const int nx = jobs.N[z] >> 5;
    const int n0 = (t % nx) << 5, k0 = (t / nx) << 5;
    const int K = jobs.K[z], N = jobs.N[z];
    __shared__ float tt[32][33];
    const int tx = tid & 31, ty = tid >> 5;
    const float* src = jobs.src[z];
    #pragma unroll
    for(int i=0;i<4;i++)
      tt[ty + i*8][tx] = src[(long long)(k0 + ty + i*8) * N + n0 + tx];
    __syncthreads();
    unsigned short* dst = (unsigned short*)(ws + jobs.dst[z]);
    const int rm = jobs.rowmul[z], ro = jobs.rowoff[z];
    #pragma unroll
    for(int i=0;i<4;i++)
      dst[(long long)((n0 + ty + i*8)*rm + ro) * K + k0 + tx] = f2bf(tt[tx][ty + i*8]);
    return;
  }
  if(bid >= 10816){
    int t = (bid - 10816) * 256 + tid;
    float v = 0.f;
    if(t < 768) v = agb[t];
    else if(t >= 1536 && t < 2304) v = fgb[t - 1536];
    bias1[t] = v;
    biasq[t] = (t < 768) ? bq[t] : 0.f;
    if(t < 1536) biasg[t] = (t < 768) ? gtb[t] : fgtb[t - 768];
    return;
  }
  // ---- LN row ----
  const int row = bid - 9792;
  const float* xr = x + (long long)row * 768;
  const float* sr = sc + (long long)row * 768;
  float xs[3], ss[3];
  float s0=0.f, s1=0.f, s2=0.f, s3=0.f;
  #pragma unroll
  for(int i=0;i<3;i++){
    float xv = xr[tid + i*256], sv = sr[tid + i*256];
    xs[i]=xv; ss[i]=sv;
    s0 += xv; s1 += xv*xv; s2 += sv; s3 += sv*sv;
  }
  #pragma unroll
  for(int o=32;o;o>>=1){
    s0 += __shfl_xor(s0,o); s1 += __shfl_xor(s1,o);
    s2 += __shfl_xor(s2,o); s3 += __shfl_xor(s3,o);
  }
  __shared__ float red[4][4];
  const int w = tid >> 6;
  if((tid & 63) == 0){ red[0][w]=s0; red[1][w]=s1; red[2][w]=s2; red[3][w]=s3; }
  __syncthreads();
  float tx0 = red[0][0]+red[0][1]+red[0][2]+red[0][3];
  float tx1 = red[1][0]+red[1][1]+red[1][2]+red[1][3];
  float ts0 = red[2][0]+red[2][1]+red[2][2]+red[2][3];
  float ts1 = red[3][0]+red[3][1]+red[3][2]+red[3][3];
  const float inv = 1.f/768.f;
  float mx = tx0*inv, vx = tx1*inv - mx*mx;
  float ms = ts0*inv, vs = ts1*inv - ms*ms;
  float rsx = rsqrtf(vx + 1e-5f), rss = rsqrtf(vs + 1e-5f);
  #pragma unroll
  for(int i=0;i<3;i++){
    int c = tid + i*256;
    xa[(long long)row*768 + c]    = (xs[i]-mx)*rsx;
    sn_bf[(long long)row*768 + c] = f2bf((ss[i]-ms)*rss);
    sc_bf[(long long)row*768 + c] = f2bf(ss[i]);
  }
}

// ---------------- shared GEMM tile body (128x128, BK=32, gload_lds) --------
DEVFN void gemm_tile_f32(const unsigned short* __restrict__ A,
                         const unsigned short* __restrict__ Bt,
                         int N, int K, int m0, int n0,
                         const float* __restrict__ bias,
                         float* __restrict__ Cf, int epi,
                         unsigned short* sA, unsigned short* sB, int tid){
  const int w = tid >> 6, l = tid & 63, l15 = l & 15, l4 = l >> 4;
  const int wm = w >> 1, wn = w & 1;
  f32x4 zf = {0.f,0.f,0.f,0.f};
  f32x4 acc[4][4];
  #pragma unroll
  for(int m=0;m<4;m++)
    #pragma unroll
    for(int n=0;n<4;n++) acc[m][n] = zf;

  const int srow = w*16 + (l >> 2);
  const int scol = (l & 3) * 8;
  const unsigned short* gA = A  + (long long)(m0 + srow) * K + scol;
  const unsigned short* gB = Bt + (long long)(n0 + srow) * K + scol;
  unsigned short* lA0 = &sA[(w*16)*32];
  unsigned short* lA1 = &sA[(64 + w*16)*32];
  unsigned short* lB0 = &sB[(w*16)*32];
  unsigned short* lB1 = &sB[(64 + w*16)*32];
  const long long half = (long long)64 * K;

  for(int k0 = 0; k0 < K; k0 += 32){
    gload16(gA + k0, lA0);
    gload16(gA + half + k0, lA1);
    gload16(gB + k0, lB0);
    gload16(gB + half + k0, lB1);
    __syncthreads();
    bf16x8 af[4], bg[4];
    #pragma unroll
    for(int m=0;m<4;m++) af[m] = *(const bf16x8*)&sA[(wm*64 + m*16 + l15)*32 + l4*8];
    #pragma unroll
    for(int n=0;n<4;n++) bg[n] = *(const bf16x8*)&sB[(wn*64 + n*16 + l15)*32 + l4*8];
    #pragma unroll
    for(int m=0;m<4;m++)
      #pragma unroll
      for(int n=0;n<4;n++)
        acc[m][n] = __builtin_amdgcn_mfma_f32_16x16x32_bf16(af[m], bg[n], acc[m][n], 0, 0, 0);
    __syncthreads();
  }
  #pragma unroll
  for(int m=0;m<4;m++){
    #pragma unroll
    for(int n=0;n<4;n++){
      #pragma unroll
      for(int r=0;r<4;r++){
        const int i = m0 + wm*64 + m*16 + l4*4 + r;
        const int c = n0 + wn*64 + n*16 + l15;
        float v = acc[m][n][r] + bias[c];
        Cf[(long long)i*N + c] = epi ? sigf(v) : v;
      }
    }
  }
}

// ---------------- pair-bias block: LDS-staged, coalesced, swizzled ----------
// Block covers 256 rows. Per q-iter: stage 64 rows (32KB) via global_load_lds
// with inverse-swizzled SOURCE (col ^= (row&15)<<4), linear LDS dest; read
// fragments with the same XOR. Each wave computes 16 rows x 16 heads via MFMA.
DEVFN void pair_block(int pbid, const float* __restrict__ pair,
                      const float* __restrict__ wb,
                      unsigned short* __restrict__ pb, int tid, char* lds){
  const int l = tid & 63, w = tid >> 6, l15 = l & 15, l4 = l >> 4;
  bf16x8 wbf[4];
  #pragma unroll
  for(int c=0;c<4;c++){
    bf16x8 t;
    #pragma unroll
    for(int e=0;e<8;e++) t[e] = (short)f2bf(wb[(c*32 + l4*8 + e)*16 + l15]);
    wbf[c] = t;
  }
  const long long blockrow0 = (long long)pbid * 256;
  for(int q=0;q<4;q++){
    // ---- stage rows [q*64, q*64+64): 8 issues x 4KB, coalesced 1KB/wave ----
    const char* gbase = (const char*)(pair + ((blockrow0 + q*64) << 7));
    #pragma unroll
    for(int is=0; is<8; is++){
      const int r   = is*8 + w*2 + (l >> 5);        // staged row 0..63
      const int col = (l & 31) * 16;                // byte col 0..496
      gload16(gbase + (r << 9) + (col ^ ((r & 15) << 4)),
              lds + is*4096 + w*1024);
    }
    __syncthreads();
    // ---- fragment read (swizzled) + LN + MFMA ----
    const int rr = w*16 + l15;                      // this lane's staged row
    const char* rowp = lds + (rr << 9);
    const int sw = (rr & 15) << 4;
    float vals[32];
    #pragma unroll
    for(int c=0;c<4;c++){
      const int x = c*128 + l4*32;
      float4 v0 = *(const float4*)(rowp + (x ^ sw));
      float4 v1 = *(const float4*)(rowp + ((x + 16) ^ sw));
      vals[c*8+0]=v0.x; vals[c*8+1]=v0.y; vals[c*8+2]=v0.z; vals[c*8+3]=v0.w;
      vals[c*8+4]=v1.x; vals[c*8+5]=v1.y; vals[c*8+6]=v1.z; vals[c*8+7]=v1.w;
    }
    float s=0.f, s2=0.f;
    #pragma unroll
    for(int e=0;e<32;e++){ s += vals[e]; s2 += vals[e]*vals[e]; }
    s += __shfl_xor(s, 16); s2 += __shfl_xor(s2, 16);
    s += __shfl_xor(s, 32); s2 += __shfl_xor(s2, 32);
    const float m = s * (1.f/128.f);
    const float rs = rsqrtf(s2*(1.f/128.f) - m*m + 1e-5f);
    f32x4 acc = {0.f,0.f,0.f,0.f};
    #pragma unroll
    for(int c=0;c<4;c++){
      bf16x8 af;
      #pragma unroll
      for(int e=0;e<8;e++) af[e] = (short)f2bf_trunc((vals[c*8+e] - m) * rs);
      acc = __builtin_amdgcn_mfma_f32_16x16x32_bf16(af, wbf[c], acc, 0,0,0);
    }
    const long long row0 = blockrow0 + q*64 + w*16;
    us4 o;
    #pragma unroll
    for(int r=0;r<4;r++) o[r] = f2bf(acc[r]);
    *(us4*)&pb[((long long)l15 << 20) + row0 + l4*4] = o;
    __syncthreads();
  }
}

// ---------------- fA: G1 GEMM + gates GEMM + pair rows [0,512) -------------
__global__ __launch_bounds__(256) void fA_kernel(
    const float* __restrict__ pair, const float* __restrict__ wb,
    unsigned short* __restrict__ pb,
    const unsigned short* __restrict__ SN, const unsigned short* __restrict__ W1,
    const float* __restrict__ B1, float* __restrict__ G1,
    const unsigned short* __restrict__ SC, const unsigned short* __restrict__ W2,
    const float* __restrict__ BG, float* __restrict__ GT){
  __shared__ __align__(16) unsigned short smem[16384];   // 32 KB
  const int bid = blockIdx.x;
  const int tid = threadIdx.x;
  if(bid < 288){
    if(bid < 192){
      gemm_tile_f32(SN, W1, 3072, 768, (bid & 7)*128, (bid >> 3)*128, B1, G1, 0,
                    smem, smem + 4096, tid);
    } else {
      const int t = bid - 192;
      gemm_tile_f32(SC, W2, 1536, 768, (t & 7)*128, (t >> 3)*128, BG, GT, 1,
                    smem, smem + 4096, tid);
    }
    return;
  }
  pair_block(bid - 288, pair, wb, pb, tid, (char*)smem);
}

// ---------------- elementwise: adaLN combine + out=x init ----------------
__global__ __launch_bounds__(256) void ew1_kernel(const float* __restrict__ g1,
    const float* __restrict__ xa, unsigned short* __restrict__ a_bf,
    unsigned short* __restrict__ f_bf, const float* __restrict__ x,
    float* __restrict__ out){
  const int i = blockIdx.x;
  const int c = blockIdx.y * 256 + threadIdx.x;
  const float* row = g1 + (long long)i * 3072;
  float xv = xa[(long long)i*768 + c];
  a_bf[(long long)i*768 + c] = f2bf(sigf(row[c])      * xv + row[768 + c]);
  f_bf[(long long)i*768 + c] = f2bf(sigf(row[1536+c]) * xv + row[2304 + c]);
  out[(long long)i*768 + c] = x[(long long)i*768 + c];
}

// ---------------- fB: QKVG GEMM (head-major out) + HH GEMM + pair ----------
__global__ __launch_bounds__(256) void fB_kernel(
    const float* __restrict__ pair, const float* __restrict__ wb,
    unsigned short* __restrict__ pb,
    const unsigned short* __restrict__ A_, const unsigned short* __restrict__ W3,
    const float* __restrict__ BQ,
    unsigned short* __restrict__ QH, unsigned short* __restrict__ KH,
    unsigned short* __restrict__ GH, unsigned short* __restrict__ VT,
    const unsigned short* __restrict__ F_, const unsigned short* __restrict__ W4,
    unsigned short* __restrict__ HH){
  __shared__ __align__(16) unsigned short smem[16384];   // 32 KB
  const int bid = blockIdx.x;
  const int tid = threadIdx.x;
  if(bid >= 384){
    pair_block(bid - 384 + 2048, pair, wb, pb, tid, (char*)smem);
    return;
  }
  unsigned short* sA = smem;
  unsigned short* sB = smem + 4096;
  const bool isq = bid < 192;
  const int t = isq ? bid : bid - 192;
  const int m0 = (t & 7) * 128, n0 = (t >> 3) * 128;
  const unsigned short* A  = isq ? A_ : F_;
  const unsigned short* Bt = isq ? W3 : W4;
  const int K = 768;

  const int w = tid >> 6, l = tid & 63, l15 = l & 15, l4 = l >> 4;
  const int wm = w >> 1, wn = w & 1;
  f32x4 zf = {0.f,0.f,0.f,0.f};
  f32x4 acc[4][4];
  #pragma unroll
  for(int m=0;m<4;m++)
    #pragma unroll
    for(int n=0;n<4;n++) acc[m][n] = zf;

  const int srow = w*16 + (l >> 2);
  const int scol = (l & 3) * 8;
  const unsigned short* gA = A  + (long long)(m0 + srow) * K + scol;
  const unsigned short* gB = Bt + (long long)(n0 + srow) * K + scol;
  unsigned short* lA0 = &sA[(w*16)*32];
  unsigned short* lA1 = &sA[(64 + w*16)*32];
  unsigned short* lB0 = &sB[(w*16)*32];
  unsigned short* lB1 = &sB[(64 + w*16)*32];
  const long long half = (long long)64 * K;

  for(int k0 = 0; k0 < K; k0 += 32){
    gload16(gA + k0, lA0);
    gload16(gA + half + k0, lA1);
    gload16(gB + k0, lB0);
    gload16(gB + half + k0, lB1);
    __syncthreads();
    bf16x8 af[4], bg[4];
    #pragma unroll
    for(int m=0;m<4;m++) af[m] = *(const bf16x8*)&sA[(wm*64 + m*16 + l15)*32 + l4*8];
    #pragma unroll
    for(int n=0;n<4;n++) bg[n] = *(const bf16x8*)&sB[(wn*64 + n*16 + l15)*32 + l4*8];
    #pragma unroll
    for(int m=0;m<4;m++)
      #pragma unroll
      for(int n=0;n<4;n++)
        acc[m][n] = __builtin_amdgcn_mfma_f32_16x16x32_bf16(af[m], bg[n], acc[m][n], 0, 0, 0);
    __syncthreads();
  }
  if(isq){
    #pragma unroll
    for(int m=0;m<4;m++){
      #pragma unroll
      for(int n=0;n<4;n++){
        const int c = n0 + wn*64 + n*16 + l15;
        const int ibase = m0 + wm*64 + m*16 + l4*4;
        const int which = c / 768;           // 0=q 1=k 2=v 3=g
        const int h = (c % 768) / 48, d = c % 48;
        unsigned short vb[4];
        #pragma unroll
        for(int r=0;r<4;r++) vb[r] = f2bf(acc[m][n][r] + BQ[c]);
        if(which == 2){
          us4 o; o.x=vb[0]; o.y=vb[1]; o.z=vb[2]; o.w=vb[3];
          *(us4*)&VT[((long long)(c - 1536) << 10) + ibase] = o;
        } else {
          unsigned short* dst = (which == 0) ? QH : (which == 1) ? KH : GH;
          #pragma unroll
          for(int r=0;r<4;r++)
            dst[((long long)((h << 10) + ibase + r))*48 + d] = vb[r];
        }
      }
    }
  } else {
    #pragma unroll
    for(int m=0;m<4;m++){
      #pragma unroll
      for(int n=0;n<4;n++){
        #pragma unroll
        for(int r=0;r<4;r++){
          const int i = m0 + wm*64 + m*16 + l4*4 + r;
          const int c = n0 + wn*64 + n*16 + l15;
          float v = acc[m][n][r];
          float partner = __shfl_xor(v, 1);
          if((c & 1) == 0)
            HH[(long long)i*1536 + (c>>1)] = f2bf(v * sigf(v) * partner);
        }
      }
    }
  }
}

// ---------------- attention: per (head, 16-row tile), head-major layouts ---
__global__ __launch_bounds__(256) void attn_kernel(
    const unsigned short* __restrict__ QH, const unsigned short* __restrict__ KH,
    const unsigned short* __restrict__ GH,
    const unsigned short* __restrict__ pbias,
    const unsigned short* __restrict__ VT,
    unsigned short* __restrict__ go){
  const int h  = blockIdx.x >> 6;
  const int i0 = (blockIdx.x & 63) << 4;
  const int tid = threadIdx.x;
  const int w = tid >> 6, l = tid & 63, l15 = l & 15, l4 = l >> 4;

  __shared__ unsigned short sP[16][1032];
  __shared__ float sRedM[16][4];
  __shared__ float sRedS[16][4];
  __shared__ float sO[4][16][48];

  f32x4 zf = {0.f,0.f,0.f,0.f};
  bf16x8 zero8 = {0,0,0,0,0,0,0,0};

  const unsigned short* pbh = pbias + ((long long)h << 20) + ((long long)i0 << 10);
  #pragma unroll
  for(int it=0; it<8; it++){
    const int idx = it*2048 + tid*8;
    const int r = idx >> 10, c = idx & 1023;
    *(bf16x8*)&sP[r][c] = *(const bf16x8*)&pbh[((long long)r << 10) + c];
  }

  // ---- QK^T ----
  f32x4 accs[16];
  #pragma unroll
  for(int f=0;f<16;f++) accs[f] = zf;
  bf16x8 aq0, aq1;
  {
    const unsigned short* qp = QH + (long long)((h << 10) + i0 + l15)*48;
    aq0 = *(const bf16x8*)(qp + l4*8);
    aq1 = *(const bf16x8*)(qp + 32 + l4*8);
  }
  const int jbase = w * 256;
  #pragma unroll
  for(int f=0; f<16; f++){
    const int j = jbase + f*16 + l15;
    const unsigned short* kp = KH + (long long)((h << 10) + j)*48;
    bf16x8 bk0 = *(const bf16x8*)(kp + l4*8);
    bf16x8 bk1 = *(const bf16x8*)(kp + 32 + l4*8);
    if(l4 >= 2) bk1 = zero8;
    accs[f] = __builtin_amdgcn_mfma_f32_16x16x32_bf16(aq0, bk0, accs[f], 0,0,0);
    accs[f] = __builtin_amdgcn_mfma_f32_16x16x32_bf16(aq1, bk1, accs[f], 0,0,0);
  }
  __syncthreads();   // sP bias staged

  const float scale = 0.14433756729740643f;  // 1/sqrt(48)
  #pragma unroll
  for(int f=0;f<16;f++){
    #pragma unroll
    for(int r=0;r<4;r++)
      accs[f][r] = accs[f][r]*scale + bf2f(sP[l4*4 + r][jbase + f*16 + l15]);
  }
  // ---- softmax (unnormalized) ----
  float pm[4];
  #pragma unroll
  for(int r=0;r<4;r++){
    float m = accs[0][r];
    #pragma unroll
    for(int f=1;f<16;f++) m = fmaxf(m, accs[f][r]);
    #pragma unroll
    for(int o=1;o<16;o<<=1) m = fmaxf(m, __shfl_xor(m, o));
    pm[r] = m;
  }
  if(l15 == 0){
    #pragma unroll
    for(int r=0;r<4;r++) sRedM[l4*4 + r][w] = pm[r];
  }
  __syncthreads();
  float rowm[4];
  #pragma unroll
  for(int r=0;r<4;r++){
    const int i = l4*4 + r;
    rowm[r] = fmaxf(fmaxf(sRedM[i][0], sRedM[i][1]), fmaxf(sRedM[i][2], sRedM[i][3]));
  }
  float psum[4] = {0.f,0.f,0.f,0.f};
  #pragma unroll
  for(int f=0;f<16;f++)
    #pragma unroll
    for(int r=0;r<4;r++){
      float p = __expf(accs[f][r] - rowm[r]);
      accs[f][r] = p;
      psum[r] += p;
    }
  #pragma unroll
  for(int r=0;r<4;r++)
    #pragma unroll
    for(int o=1;o<16;o<<=1) psum[r] += __shfl_xor(psum[r], o);
  if(l15 == 0){
    #pragma unroll
    for(int r=0;r<4;r++) sRedS[l4*4 + r][w] = psum[r];
  }
  #pragma unroll
  for(int f=0;f<16;f++)
    #pragma unroll
    for(int r=0;r<4;r++)
      sP[l4*4 + r][jbase + f*16 + l15] = f2bf(accs[f][r]);

  // ---- PV: B-frags straight from global VT (L2-hot) ----
  f32x4 acco[3];
  #pragma unroll
  for(int n=0;n<3;n++) acco[n] = zf;
  const unsigned short* vth = VT + ((long long)(h*48) << 10);
  #pragma unroll
  for(int c=0; c<4; c++){
    const int jb = jbase + c*64;
    #pragma unroll
    for(int kk=0; kk<2; kk++){
      bf16x8 pa = *(const bf16x8*)&sP[l15][jb + kk*32 + l4*8];
      #pragma unroll
      for(int n=0;n<3;n++){
        bf16x8 bv = *(const bf16x8*)&vth[((long long)(n*16 + l15) << 10) + jb + kk*32 + l4*8];
        acco[n] = __builtin_amdgcn_mfma_f32_16x16x32_bf16(pa, bv, acco[n], 0,0,0);
      }
    }
  }
  #pragma unroll
  for(int n=0;n<3;n++)
    #pragma unroll
    for(int r=0;r<4;r++)
      sO[w][l4*4 + r][n*16 + l15] = acco[n][r];
  __syncthreads();
  for(int t = tid; t < 768; t += 256){
    const int i = t / 48, d = t % 48;
    float o = sO[0][i][d] + sO[1][i][d] + sO[2][i][d] + sO[3][i][d];
    float lsum = sRedS[i][0] + sRedS[i][1] + sRedS[i][2] + sRedS[i][3];
    float gv = bf2f(GH[(long long)((h << 10) + i0 + i)*48 + d]);
    go[(long long)(i0 + i)*768 + h*48 + d] = f2bf(sigf(gv) * (o / lsum));
  }
}

// ---------------- final: out += gA*(GO@W6) + gF*(HH@W5), split-K ----------
__global__ __launch_bounds__(256) void final_kernel(
    const unsigned short* __restrict__ GO, const unsigned short* __restrict__ W6t,
    const unsigned short* __restrict__ HH, const unsigned short* __restrict__ W5t,
    const float* __restrict__ gates, float* __restrict__ out){
  __shared__ __align__(16) unsigned short sA[128*32];
  __shared__ __align__(16) unsigned short sB[128*32];
  const int m0 = blockIdx.x * 128, n0 = blockIdx.y * 128;
  const int z = blockIdx.z;
  const bool pA = z < 4;
  const unsigned short* A  = pA ? GO  : HH;
  const unsigned short* Bt = pA ? W6t : W5t;
  const int K    = pA ? 768 : 1536;
  const int kbeg = pA ? z*192 : (z-4)*384;
  const int kend = pA ? kbeg + 192 : kbeg + 384;
  const int goff = pA ? 0 : 768;
  const int tid = threadIdx.x;
  const int w = tid >> 6, l = tid & 63, l15 = l & 15, l4 = l >> 4;
  const int wm = w >> 1, wn = w & 1;
  f32x4 zf = {0.f,0.f,0.f,0.f};
  f32x4 acc[4][4];
  #pragma unroll
  for(int m=0;m<4;m++)
    #pragma unroll
    for(int n=0;n<4;n++) acc[m][n] = zf;

  const int srow = w*16 + (l >> 2);
  const int scol = (l & 3) * 8;
  const unsigned short* gA = A  + (long long)(m0 + srow) * K + scol;
  const unsigned short* gB = Bt + (long long)(n0 + srow) * K + scol;
  unsigned short* lA0 = &sA[(w*16)*32];
  unsigned short* lA1 = &sA[(64 + w*16)*32];
  unsigned short* lB0 = &sB[(w*16)*32];
  unsigned short* lB1 = &sB[(64 + w*16)*32];
  const long long half = (long long)64 * K;

  for(int k0 = kbeg; k0 < kend; k0 += 32){
    gload16(gA + k0, lA0);
    gload16(gA + half + k0, lA1);
    gload16(gB + k0, lB0);
    gload16(gB + half + k0, lB1);
    __syncthreads();
    bf16x8 af[4], bg[4];
    #pragma unroll
    for(int m=0;m<4;m++) af[m] = *(const bf16x8*)&sA[(wm*64 + m*16 + l15)*32 + l4*8];
    #pragma unroll
    for(int n=0;n<4;n++) bg[n] = *(const bf16x8*)&sB[(wn*64 + n*16 + l15)*32 + l4*8];
    #pragma unroll
    for(int m=0;m<4;m++)
      #pragma unroll
      for(int n=0;n<4;n++)
        acc[m][n] = __builtin_amdgcn_mfma_f32_16x16x32_bf16(af[m], bg[n], acc[m][n], 0, 0, 0);
    __syncthreads();
  }
  #pragma unroll
  for(int m=0;m<4;m++){
    #pragma unroll
    for(int n=0;n<4;n++){
      #pragma unroll
      for(int r=0;r<4;r++){
        const int i = m0 + wm*64 + m*16 + l4*4 + r;
        const int c = n0 + wn*64 + n*16 + l15;
        float v = gates[(long long)i*1536 + goff + c] * acc[m][n][r];
        __hip_atomic_fetch_add(&out[(long long)i*768 + c], v,
                               __ATOMIC_RELAXED, __HIP_MEMORY_SCOPE_AGENT);
      }
    }
  }
}

// ---------------------------------------------------------------------------
extern "C" void kernel_launch(void* const* d_in, const int* in_sizes, int n_in,
                              void* d_out, int out_size, void* d_ws, size_t ws_size,
                              hipStream_t stream){
  (void)in_sizes; (void)n_in; (void)out_size; (void)ws_size;
  const float* x    = (const float*)d_in[0];
  const float* sc   = (const float*)d_in[1];
  const float* pair = (const float*)d_in[2];
  const float* agw  = (const float*)d_in[3];
  const float* agb  = (const float*)d_in[4];
  const float* abw  = (const float*)d_in[5];
  const float* wq   = (const float*)d_in[6];
  const float* bq   = (const float*)d_in[7];
  const float* wk   = (const float*)d_in[8];
  const float* wv   = (const float*)d_in[9];
  const float* wb   = (const float*)d_in[10];
  const float* wg   = (const float*)d_in[11];
  const float* wo   = (const float*)d_in[12];
  const float* gtw  = (const float*)d_in[13];
  const float* gtb  = (const float*)d_in[14];
  const float* fgw  = (const float*)d_in[15];
  const float* fgb  = (const float*)d_in[16];
  const float* fbw  = (const float*)d_in[17];
  const float* fw1  = (const float*)d_in[18];
  const float* fw2  = (const float*)d_in[19];
  const float* fw3  = (const float*)d_in[20];
  const float* fgtw = (const float*)d_in[21];
  const float* fgtb = (const float*)d_in[22];
  float* out = (float*)d_out;
  char* ws = (char*)d_ws;

  unsigned short* SN   = (unsigned short*)(ws + OFF_SN);
  unsigned short* SC   = (unsigned short*)(ws + OFF_SC);
  float*          XA   = (float*)(ws + OFF_XA);
  unsigned short* W1   = (unsigned short*)(ws + OFF_W1);
  unsigned short* W2   = (unsigned short*)(ws + OFF_W2);
  unsigned short* W3   = (unsigned short*)(ws + OFF_W3);
  unsigned short* W4   = (unsigned short*)(ws + OFF_W4);
  unsigned short* W5   = (unsigned short*)(ws + OFF_W5);
  unsigned short* W6   = (unsigned short*)(ws + OFF_W6);
  float*          B1   = (float*)(ws + OFF_BIAS1);
  float*          BG   = (float*)(ws + OFF_BIASG);
  float*          BQ   = (float*)(ws + OFF_BIASQ);
  float*          G1   = (float*)(ws + OFF_G1);
  float*          GT   = (float*)(ws + OFF_GATES);
  unsigned short* A_   = (unsigned short*)(ws + OFF_A);
  unsigned short* F_   = (unsigned short*)(ws + OFF_F);
  unsigned short* QH   = (unsigned short*)(ws + OFF_QH);
  unsigned short* KH   = (unsigned short*)(ws + OFF_KH);
  unsigned short* GH   = (unsigned short*)(ws + OFF_GH);
  unsigned short* VT   = (unsigned short*)(ws + OFF_VT);
  unsigned short* HH   = (unsigned short*)(ws + OFF_HH);
  unsigned short* GO   = (unsigned short*)(ws + OFF_GO);
  unsigned short* PB   = (unsigned short*)(ws + OFF_PB);

  WJobs jobs;
  int ji = 0;
  auto setj = [&](const float* s, unsigned long long off, int K, int N,
                  int rm = 1, int ro = 0){
    jobs.src[ji]=s; jobs.dst[ji]=off; jobs.K[ji]=K; jobs.N[ji]=N;
    jobs.rowmul[ji]=rm; jobs.rowoff[ji]=ro; ji++;
  };
  const unsigned long long W768 = 768ULL*768ULL*2ULL;
  setj(agw,  OFF_W1 + 0*W768, 768, 768);
  setj(abw,  OFF_W1 + 1*W768, 768, 768);
  setj(fgw,  OFF_W1 + 2*W768, 768, 768);
  setj(fbw,  OFF_W1 + 3*W768, 768, 768);
  setj(gtw,  OFF_W2 + 0*W768, 768, 768);
  setj(fgtw, OFF_W2 + 1*W768, 768, 768);
  setj(wq,   OFF_W3 + 0*W768, 768, 768);
  setj(wk,   OFF_W3 + 1*W768, 768, 768);
  setj(wv,   OFF_W3 + 2*W768, 768, 768);
  setj(wg,   OFF_W3 + 3*W768, 768, 768);
  setj(fw1,  OFF_W4, 768, 1536, 2, 0);   // interleaved: row 2c   = w1 col c
  setj(fw2,  OFF_W4, 768, 1536, 2, 1);   //              row 2c+1 = w2 col c
  setj(fw3,  OFF_W5, 1536, 768);
  setj(wo,   OFF_W6, 768, 768);

  // prep: 9792 transpose + 1024 LN + 12 bias
  prep_kernel<<<10828, 256, 0, stream>>>(jobs, ws, x, sc, SN, SC, XA,
      agb, bq, gtb, fgtb, fgb, B1, BG, BQ);
  // fA: G1 + gates GEMMs (288, front) + pair rows [0,512) (2048)
  fA_kernel<<<2336, 256, 0, stream>>>(pair, wb, PB, SN, W1, B1, G1, SC, W2, BG, GT);
  // adaLN combine -> a, f (bf16); also out = x
  ew1_kernel<<<dim3(1024,3), 256, 0, stream>>>(G1, XA, A_, F_, x, out);
  // fB: QKVG(head-major)+HH GEMMs (384, front) + pair [512,1024)
  fB_kernel<<<2432, 256, 0, stream>>>(pair, wb, PB, A_, W3, BQ,
      QH, KH, GH, VT, F_, W4, HH);
  // attention -> go = sigmoid(g)*o (bf16)
  attn_kernel<<<1024, 256, 0, stream>>>(QH, KH, GH, PB, VT, GO);
  // out += gateA*(GO@wo) + gateF*(HH@w3)   (split-K atomics)
  final_kernel<<<dim3(8,6,8), 256, 0, stream>>>(GO, W6, HH, W5, GT, out);
}

// Round 11
// 265.009 us; speedup vs baseline: 1.1515x; 1.0801x over previous
//
#include <hip/hip_runtime.h>
#include <hip/hip_bf16.h>

// ---------------------------------------------------------------------------
// DiffusionModule: AttentionPairBias + ConditionedFeedForward (AF3-style)
// B=1, N=1024, DS=768, DP=128, H=16, DH=48, DFF=1536. f32 in/out, bf16 MFMA.
// R11 = R6 + (W3-W6 transposes into fA) + (HH@W5 final-half into attn launch).
// Pair stream = R6 register-load form (R8/R9/R10 stream experiments all null).
// ---------------------------------------------------------------------------

typedef __attribute__((ext_vector_type(8))) short bf16x8;
typedef __attribute__((ext_vector_type(4))) float f32x4;
typedef __attribute__((ext_vector_type(4))) unsigned short us4;

#define DEVFN static __device__ __forceinline__

DEVFN float bf2f(unsigned short u){
  union { unsigned int u; float f; } v; v.u = ((unsigned int)u) << 16; return v.f;
}
DEVFN unsigned short f2bf(float f){
  union { float f; unsigned int u; } v; v.f = f;
  unsigned int r = v.u + 0x7fffu + ((v.u >> 16) & 1u);
  return (unsigned short)(r >> 16);
}
DEVFN unsigned short f2bf_trunc(float f){
  union { float f; unsigned int u; } v; v.f = f;
  return (unsigned short)(v.u >> 16);
}
DEVFN float sigf(float x){ return 1.f / (1.f + __expf(-x)); }

DEVFN void gload16(const void* g, void* l){
  __builtin_amdgcn_global_load_lds(
      (const __attribute__((address_space(1))) void*)g,
      (__attribute__((address_space(3))) void*)l, 16, 0, 0);
}

// ---------------- workspace layout (bytes) ----------------
#define OFF_SN    0x0000000ULL
#define OFF_SC    0x0180000ULL
#define OFF_XA    0x0300000ULL
#define OFF_W1    0x0600000ULL
#define OFF_W2    0x0A80000ULL
#define OFF_W3    0x0CC0000ULL
#define OFF_W4    0x1140000ULL
#define OFF_W5    0x15C0000ULL
#define OFF_W6    0x1800000ULL
#define OFF_BIAS1 0x1920000ULL
#define OFF_BIASG 0x1923000ULL
#define OFF_BIASQ 0x1924800ULL
#define OFF_G1    0x1930000ULL
#define OFF_GATES 0x2530000ULL
#define OFF_A     0x2B30000ULL
#define OFF_F     0x2CB0000ULL
#define OFF_QH    0x2E30000ULL
#define OFF_KH    0x2FB0000ULL
#define OFF_GH    0x3130000ULL
#define OFF_VT    0x3430000ULL
#define OFF_HH    0x4030000ULL
#define OFF_GO    0x4330000ULL
#define OFF_PB    0x47B0000ULL

struct WJobs {
  const float* src[8];
  unsigned long long dst[8];
  int K[8];
  int N[8];
  int rowmul[8];
  int rowoff[8];
};

// ---------------- transpose tile: dst[n*rm+ro][k] = bf16(src[k][n]) --------
DEVFN void transpose_tile(const WJobs& jobs, char* ws, int t, int tid, void* smem){
  int z = 0;
  while(true){
    int nt = (jobs.N[z] >> 5) * (jobs.K[z] >> 5);
    if(t < nt) break;
    t -= nt; z++;
  }
  const int nx = jobs.N[z] >> 5;
  const int n0 = (t % nx) << 5, k0 = (t / nx) << 5;
  const int K = jobs.K[z], N = jobs.N[z];
  float (*tt)[33] = (float(*)[33])smem;
  const int tx = tid & 31, ty = tid >> 5;
  const float* src = jobs.src[z];
  #pragma unroll
  for(int i=0;i<4;i++)
    tt[ty + i*8][tx] = src[(long long)(k0 + ty + i*8) * N + n0 + tx];
  __syncthreads();
  unsigned short* dst = (unsigned short*)(ws + jobs.dst[z]);
  const int rm = jobs.rowmul[z], ro = jobs.rowoff[z];
  #pragma unroll
  for(int i=0;i<4;i++)
    dst[(long long)((n0 + ty + i*8)*rm + ro) * K + k0 + tx] = f2bf(tt[tx][ty + i*8]);
}

// ---------------- prep: W1/W2 transpose + LN rows + bias build -------------
// grid 4492: [0,3456) transpose, [3456,4480) LN, [4480,4492) bias.
__global__ __launch_bounds__(256) void prep_kernel(WJobs jobsP, char* ws,
    const float* __restrict__ x, const float* __restrict__ sc,
    unsigned short* __restrict__ sn_bf, unsigned short* __restrict__ sc_bf,
    float* __restrict__ xa,
    const float* agb, const float* bq, const float* gtb, const float* fgtb,
    const float* fgb, float* bias1, float* biasg, float* biasq){
  __shared__ __align__(16) char smem[4352];
  const int bid = blockIdx.x;
  const int tid = threadIdx.x;
  if(bid < 3456){
    transpose_tile(jobsP, ws, bid, tid, smem);
    return;
  }
  if(bid >= 4480){
    int t = (bid - 4480) * 256 + tid;
    float v = 0.f;
    if(t < 768) v = agb[t];
    else if(t >= 1536 && t < 2304) v = fgb[t - 1536];
    bias1[t] = v;
    biasq[t] = (t < 768) ? bq[t] : 0.f;
    if(t < 1536) biasg[t] = (t < 768) ? gtb[t] : fgtb[t - 768];
    return;
  }
  // ---- LN row ----
  const int row = bid - 3456;
  const float* xr = x + (long long)row * 768;
  const float* sr = sc + (long long)row * 768;
  float xs[3], ss[3];
  float s0=0.f, s1=0.f, s2=0.f, s3=0.f;
  #pragma unroll
  for(int i=0;i<3;i++){
    float xv = xr[tid + i*256], sv = sr[tid + i*256];
    xs[i]=xv; ss[i]=sv;
    s0 += xv; s1 += xv*xv; s2 += sv; s3 += sv*sv;
  }
  #pragma unroll
  for(int o=32;o;o>>=1){
    s0 += __shfl_xor(s0,o); s1 += __shfl_xor(s1,o);
    s2 += __shfl_xor(s2,o); s3 += __shfl_xor(s3,o);
  }
  float (*red)[4] = (float(*)[4])smem;
  const int w = tid >> 6;
  if((tid & 63) == 0){ red[0][w]=s0; red[1][w]=s1; red[2][w]=s2; red[3][w]=s3; }
  __syncthreads();
  float tx0 = red[0][0]+red[0][1]+red[0][2]+red[0][3];
  float tx1 = red[1][0]+red[1][1]+red[1][2]+red[1][3];
  float ts0 = red[2][0]+red[2][1]+red[2][2]+red[2][3];
  float ts1 = red[3][0]+red[3][1]+red[3][2]+red[3][3];
  const float inv = 1.f/768.f;
  float mx = tx0*inv, vx = tx1*inv - mx*mx;
  float ms = ts0*inv, vs = ts1*inv - ms*ms;
  float rsx = rsqrtf(vx + 1e-5f), rss = rsqrtf(vs + 1e-5f);
  #pragma unroll
  for(int i=0;i<3;i++){
    int c = tid + i*256;
    xa[(long long)row*768 + c]    = (xs[i]-mx)*rsx;
    sn_bf[(long long)row*768 + c] = f2bf((ss[i]-ms)*rss);
    sc_bf[(long long)row*768 + c] = f2bf(ss[i]);
  }
}

// ---------------- shared GEMM tile body (128x128, BK=32, gload_lds) --------
DEVFN void gemm_tile_f32(const unsigned short* __restrict__ A,
                         const unsigned short* __restrict__ Bt,
                         int N, int K, int m0, int n0,
                         const float* __restrict__ bias,
                         float* __restrict__ Cf, int epi,
                         unsigned short* sA, unsigned short* sB, int tid){
  const int w = tid >> 6, l = tid & 63, l15 = l & 15, l4 = l >> 4;
  const int wm = w >> 1, wn = w & 1;
  f32x4 zf = {0.f,0.f,0.f,0.f};
  f32x4 acc[4][4];
  #pragma unroll
  for(int m=0;m<4;m++)
    #pragma unroll
    for(int n=0;n<4;n++) acc[m][n] = zf;

  const int srow = w*16 + (l >> 2);
  const int scol = (l & 3) * 8;
  const unsigned short* gA = A  + (long long)(m0 + srow) * K + scol;
  const unsigned short* gB = Bt + (long long)(n0 + srow) * K + scol;
  unsigned short* lA0 = &sA[(w*16)*32];
  unsigned short* lA1 = &sA[(64 + w*16)*32];
  unsigned short* lB0 = &sB[(w*16)*32];
  unsigned short* lB1 = &sB[(64 + w*16)*32];
  const long long half = (long long)64 * K;

  for(int k0 = 0; k0 < K; k0 += 32){
    gload16(gA + k0, lA0);
    gload16(gA + half + k0, lA1);
    gload16(gB + k0, lB0);
    gload16(gB + half + k0, lB1);
    __syncthreads();
    bf16x8 af[4], bg[4];
    #pragma unroll
    for(int m=0;m<4;m++) af[m] = *(const bf16x8*)&sA[(wm*64 + m*16 + l15)*32 + l4*8];
    #pragma unroll
    for(int n=0;n<4;n++) bg[n] = *(const bf16x8*)&sB[(wn*64 + n*16 + l15)*32 + l4*8];
    #pragma unroll
    for(int m=0;m<4;m++)
      #pragma unroll
      for(int n=0;n<4;n++)
        acc[m][n] = __builtin_amdgcn_mfma_f32_16x16x32_bf16(af[m], bg[n], acc[m][n], 0, 0, 0);
    __syncthreads();
  }
  #pragma unroll
  for(int m=0;m<4;m++){
    #pragma unroll
    for(int n=0;n<4;n++){
      #pragma unroll
      for(int r=0;r<4;r++){
        const int i = m0 + wm*64 + m*16 + l4*4 + r;
        const int c = n0 + wn*64 + n*16 + l15;
        float v = acc[m][n][r] + bias[c];
        Cf[(long long)i*N + c] = epi ? sigf(v) : v;
      }
    }
  }
}

// ---------------- pair-bias block (256 (i,j) rows via MFMA, R6 form) -------
DEVFN void pair_block(int pbid, const float* __restrict__ pair,
                      const float* __restrict__ wb,
                      unsigned short* __restrict__ pb, int tid){
  const int l = tid & 63, w = tid >> 6, l15 = l & 15, l4 = l >> 4;
  bf16x8 wbf[4];
  #pragma unroll
  for(int c=0;c<4;c++){
    bf16x8 t;
    #pragma unroll
    for(int e=0;e<8;e++) t[e] = (short)f2bf(wb[(c*32 + l4*8 + e)*16 + l15]);
    wbf[c] = t;
  }
  #pragma unroll
  for(int q=0;q<4;q++){
    const long long row0 = (((long long)pbid) * 16 + q*4 + w) << 4;
    const float* pr = pair + ((row0 + l15) << 7);
    float vals[32];
    #pragma unroll
    for(int c=0;c<4;c++){
      float4 v0 = *(const float4*)(pr + c*32 + l4*8);
      float4 v1 = *(const float4*)(pr + c*32 + l4*8 + 4);
      vals[c*8+0]=v0.x; vals[c*8+1]=v0.y; vals[c*8+2]=v0.z; vals[c*8+3]=v0.w;
      vals[c*8+4]=v1.x; vals[c*8+5]=v1.y; vals[c*8+6]=v1.z; vals[c*8+7]=v1.w;
    }
    float s=0.f, s2=0.f;
    #pragma unroll
    for(int e=0;e<32;e++){ s += vals[e]; s2 += vals[e]*vals[e]; }
    s += __shfl_xor(s, 16); s2 += __shfl_xor(s2, 16);
    s += __shfl_xor(s, 32); s2 += __shfl_xor(s2, 32);
    const float m = s * (1.f/128.f);
    const float rs = rsqrtf(s2*(1.f/128.f) - m*m + 1e-5f);
    f32x4 acc = {0.f,0.f,0.f,0.f};
    #pragma unroll
    for(int c=0;c<4;c++){
      bf16x8 af;
      #pragma unroll
      for(int e=0;e<8;e++) af[e] = (short)f2bf_trunc((vals[c*8+e] - m) * rs);
      acc = __builtin_amdgcn_mfma_f32_16x16x32_bf16(af, wbf[c], acc, 0,0,0);
    }
    us4 o;
    #pragma unroll
    for(int r=0;r<4;r++) o[r] = f2bf(acc[r]);
    *(us4*)&pb[((long long)l15 << 20) + row0 + l4*4] = o;
  }
}

// ---------------- fA: G1+gates GEMMs + W3..W6 transposes + pair [0,512) ----
// grid 8672: [0,288) GEMM, [288,6624) transpose (jobsA), [6624,8672) pair.
__global__ __launch_bounds__(256) void fA_kernel(
    WJobs jobsA, char* ws,
    const float* __restrict__ pair, const float* __restrict__ wb,
    unsigned short* __restrict__ pb,
    const unsigned short* __restrict__ SN, const unsigned short* __restrict__ W1,
    const float* __restrict__ B1, float* __restrict__ G1,
    const unsigned short* __restrict__ SC, const unsigned short* __restrict__ W2,
    const float* __restrict__ BG, float* __restrict__ GT){
  __shared__ __align__(16) unsigned short sA[128*32];
  __shared__ __align__(16) unsigned short sB[128*32];
  const int bid = blockIdx.x;
  const int tid = threadIdx.x;
  if(bid < 288){
    if(bid < 192){
      gemm_tile_f32(SN, W1, 3072, 768, (bid & 7)*128, (bid >> 3)*128, B1, G1, 0, sA, sB, tid);
    } else {
      const int t = bid - 192;
      gemm_tile_f32(SC, W2, 1536, 768, (t & 7)*128, (t >> 3)*128, BG, GT, 1, sA, sB, tid);
    }
    return;
  }
  if(bid < 6624){
    transpose_tile(jobsA, ws, bid - 288, tid, sA);
    return;
  }
  pair_block(bid - 6624, pair, wb, pb, tid);
}

// ---------------- elementwise: adaLN combine + out=x init ----------------
__global__ __launch_bounds__(256) void ew1_kernel(const float* __restrict__ g1,
    const float* __restrict__ xa, unsigned short* __restrict__ a_bf,
    unsigned short* __restrict__ f_bf, const float* __restrict__ x,
    float* __restrict__ out){
  const int i = blockIdx.x;
  const int c = blockIdx.y * 256 + threadIdx.x;
  const float* row = g1 + (long long)i * 3072;
  float xv = xa[(long long)i*768 + c];
  a_bf[(long long)i*768 + c] = f2bf(sigf(row[c])      * xv + row[768 + c]);
  f_bf[(long long)i*768 + c] = f2bf(sigf(row[1536+c]) * xv + row[2304 + c]);
  out[(long long)i*768 + c] = x[(long long)i*768 + c];
}

// ---------------- fB: QKVG GEMM (head-major out) + HH GEMM + pair ----------
__global__ __launch_bounds__(256) void fB_kernel(
    const float* __restrict__ pair, const float* __restrict__ wb,
    unsigned short* __restrict__ pb,
    const unsigned short* __restrict__ A_, const unsigned short* __restrict__ W3,
    const float* __restrict__ BQ,
    unsigned short* __restrict__ QH, unsigned short* __restrict__ KH,
    unsigned short* __restrict__ GH, unsigned short* __restrict__ VT,
    const unsigned short* __restrict__ F_, const unsigned short* __restrict__ W4,
    unsigned short* __restrict__ HH){
  __shared__ __align__(16) unsigned short sA[128*32];
  __shared__ __align__(16) unsigned short sB[128*32];
  const int bid = blockIdx.x;
  const int tid = threadIdx.x;
  if(bid >= 384){
    pair_block(bid - 384 + 2048, pair, wb, pb, tid);
    return;
  }
  const bool isq = bid < 192;
  const int t = isq ? bid : bid - 192;
  const int m0 = (t & 7) * 128, n0 = (t >> 3) * 128;
  const unsigned short* A  = isq ? A_ : F_;
  const unsigned short* Bt = isq ? W3 : W4;
  const int K = 768;

  const int w = tid >> 6, l = tid & 63, l15 = l & 15, l4 = l >> 4;
  const int wm = w >> 1, wn = w & 1;
  f32x4 zf = {0.f,0.f,0.f,0.f};
  f32x4 acc[4][4];
  #pragma unroll
  for(int m=0;m<4;m++)
    #pragma unroll
    for(int n=0;n<4;n++) acc[m][n] = zf;

  const int srow = w*16 + (l >> 2);
  const int scol = (l & 3) * 8;
  const unsigned short* gA = A  + (long long)(m0 + srow) * K + scol;
  const unsigned short* gB = Bt + (long long)(n0 + srow) * K + scol;
  unsigned short* lA0 = &sA[(w*16)*32];
  unsigned short* lA1 = &sA[(64 + w*16)*32];
  unsigned short* lB0 = &sB[(w*16)*32];
  unsigned short* lB1 = &sB[(64 + w*16)*32];
  const long long half = (long long)64 * K;

  for(int k0 = 0; k0 < K; k0 += 32){
    gload16(gA + k0, lA0);
    gload16(gA + half + k0, lA1);
    gload16(gB + k0, lB0);
    gload16(gB + half + k0, lB1);
    __syncthreads();
    bf16x8 af[4], bg[4];
    #pragma unroll
    for(int m=0;m<4;m++) af[m] = *(const bf16x8*)&sA[(wm*64 + m*16 + l15)*32 + l4*8];
    #pragma unroll
    for(int n=0;n<4;n++) bg[n] = *(const bf16x8*)&sB[(wn*64 + n*16 + l15)*32 + l4*8];
    #pragma unroll
    for(int m=0;m<4;m++)
      #pragma unroll
      for(int n=0;n<4;n++)
        acc[m][n] = __builtin_amdgcn_mfma_f32_16x16x32_bf16(af[m], bg[n], acc[m][n], 0, 0, 0);
    __syncthreads();
  }
  if(isq){
    #pragma unroll
    for(int m=0;m<4;m++){
      #pragma unroll
      for(int n=0;n<4;n++){
        const int c = n0 + wn*64 + n*16 + l15;
        const int ibase = m0 + wm*64 + m*16 + l4*4;
        const int which = c / 768;           // 0=q 1=k 2=v 3=g
        const int h = (c % 768) / 48, d = c % 48;
        unsigned short vb[4];
        #pragma unroll
        for(int r=0;r<4;r++) vb[r] = f2bf(acc[m][n][r] + BQ[c]);
        if(which == 2){
          us4 o; o.x=vb[0]; o.y=vb[1]; o.z=vb[2]; o.w=vb[3];
          *(us4*)&VT[((long long)(c - 1536) << 10) + ibase] = o;
        } else {
          unsigned short* dst = (which == 0) ? QH : (which == 1) ? KH : GH;
          #pragma unroll
          for(int r=0;r<4;r++)
            dst[((long long)((h << 10) + ibase + r))*48 + d] = vb[r];
        }
      }
    }
  } else {
    #pragma unroll
    for(int m=0;m<4;m++){
      #pragma unroll
      for(int n=0;n<4;n++){
        #pragma unroll
        for(int r=0;r<4;r++){
          const int i = m0 + wm*64 + m*16 + l4*4 + r;
          const int c = n0 + wn*64 + n*16 + l15;
          float v = acc[m][n][r];
          float partner = __shfl_xor(v, 1);
          if((c & 1) == 0)
            HH[(long long)i*1536 + (c>>1)] = f2bf(v * sigf(v) * partner);
        }
      }
    }
  }
}

// ---------------- final GEMM-slice body (split-K atomics into out) ---------
DEVFN void final_slice(const unsigned short* __restrict__ A,
                       const unsigned short* __restrict__ Bt,
                       int K, int kbeg, int kend, int goff, int m0, int n0,
                       const float* __restrict__ gates, float* __restrict__ out,
                       unsigned short* sA, unsigned short* sB, int tid){
  const int w = tid >> 6, l = tid & 63, l15 = l & 15, l4 = l >> 4;
  const int wm = w >> 1, wn = w & 1;
  f32x4 zf = {0.f,0.f,0.f,0.f};
  f32x4 acc[4][4];
  #pragma unroll
  for(int m=0;m<4;m++)
    #pragma unroll
    for(int n=0;n<4;n++) acc[m][n] = zf;

  const int srow = w*16 + (l >> 2);
  const int scol = (l & 3) * 8;
  const unsigned short* gA = A  + (long long)(m0 + srow) * K + scol;
  const unsigned short* gB = Bt + (long long)(n0 + srow) * K + scol;
  unsigned short* lA0 = &sA[(w*16)*32];
  unsigned short* lA1 = &sA[(64 + w*16)*32];
  unsigned short* lB0 = &sB[(w*16)*32];
  unsigned short* lB1 = &sB[(64 + w*16)*32];
  const long long half = (long long)64 * K;

  for(int k0 = kbeg; k0 < kend; k0 += 32){
    gload16(gA + k0, lA0);
    gload16(gA + half + k0, lA1);
    gload16(gB + k0, lB0);
    gload16(gB + half + k0, lB1);
    __syncthreads();
    bf16x8 af[4], bg[4];
    #pragma unroll
    for(int m=0;m<4;m++) af[m] = *(const bf16x8*)&sA[(wm*64 + m*16 + l15)*32 + l4*8];
    #pragma unroll
    for(int n=0;n<4;n++) bg[n] = *(const bf16x8*)&sB[(wn*64 + n*16 + l15)*32 + l4*8];
    #pragma unroll
    for(int m=0;m<4;m++)
      #pragma unroll
      for(int n=0;n<4;n++)
        acc[m][n] = __builtin_amdgcn_mfma_f32_16x16x32_bf16(af[m], bg[n], acc[m][n], 0, 0, 0);
    __syncthreads();
  }
  #pragma unroll
  for(int m=0;m<4;m++){
    #pragma unroll
    for(int n=0;n<4;n++){
      #pragma unroll
      for(int r=0;r<4;r++){
        const int i = m0 + wm*64 + m*16 + l4*4 + r;
        const int c = n0 + wn*64 + n*16 + l15;
        float v = gates[(long long)i*1536 + goff + c] * acc[m][n][r];
        __hip_atomic_fetch_add(&out[(long long)i*768 + c], v,
                               __ATOMIC_RELAXED, __HIP_MEMORY_SCOPE_AGENT);
      }
    }
  }
}

// ---------------- attn launch: [0,192) finalB (HH@W5) + [192,1216) attn ----
__global__ __launch_bounds__(256) void attn_kernel(
    const unsigned short* __restrict__ QH, const unsigned short* __restrict__ KH,
    const unsigned short* __restrict__ GH,
    const unsigned short* __restrict__ pbias,
    const unsigned short* __restrict__ VT,
    unsigned short* __restrict__ go,
    const unsigned short* __restrict__ HH, const unsigned short* __restrict__ W5t,
    const float* __restrict__ gates, float* __restrict__ out){
  __shared__ __align__(16) char smem[45824];
  const int bid = blockIdx.x;
  const int tid = threadIdx.x;
  if(bid < 192){
    // finalB: out += gateF * (HH @ W5), K=1536, 4-way split-K
    const int z = bid / 48, rem = bid % 48;
    final_slice(HH, W5t, 1536, z*384, z*384 + 384, 768,
                (rem & 7)*128, (rem >> 3)*128, gates, out,
                (unsigned short*)smem, (unsigned short*)(smem + 8192), tid);
    return;
  }
  const int it = bid - 192;
  const int h  = it >> 6;
  const int i0 = (it & 63) << 4;
  const int w = tid >> 6, l = tid & 63, l15 = l & 15, l4 = l >> 4;

  unsigned short (*sP)[1032] = (unsigned short(*)[1032])smem;      // 33024
  float (*sRedM)[4] = (float(*)[4])(smem + 33024);                 // 256
  float (*sRedS)[4] = (float(*)[4])(smem + 33280);                 // 256
  float (*sO)[16][48] = (float(*)[16][48])(smem + 33536);          // 12288

  f32x4 zf = {0.f,0.f,0.f,0.f};
  bf16x8 zero8 = {0,0,0,0,0,0,0,0};

  const unsigned short* pbh = pbias + ((long long)h << 20) + ((long long)i0 << 10);
  #pragma unroll
  for(int itr=0; itr<8; itr++){
    const int idx = itr*2048 + tid*8;
    const int r = idx >> 10, c = idx & 1023;
    *(bf16x8*)&sP[r][c] = *(const bf16x8*)&pbh[((long long)r << 10) + c];
  }

  // ---- QK^T ----
  f32x4 accs[16];
  #pragma unroll
  for(int f=0;f<16;f++) accs[f] = zf;
  bf16x8 aq0, aq1;
  {
    const unsigned short* qp = QH + (long long)((h << 10) + i0 + l15)*48;
    aq0 = *(const bf16x8*)(qp + l4*8);
    aq1 = *(const bf16x8*)(qp + 32 + l4*8);
  }
  const int jbase = w * 256;
  #pragma unroll
  for(int f=0; f<16; f++){
    const int j = jbase + f*16 + l15;
    const unsigned short* kp = KH + (long long)((h << 10) + j)*48;
    bf16x8 bk0 = *(const bf16x8*)(kp + l4*8);
    bf16x8 bk1 = *(const bf16x8*)(kp + 32 + l4*8);
    if(l4 >= 2) bk1 = zero8;
    accs[f] = __builtin_amdgcn_mfma_f32_16x16x32_bf16(aq0, bk0, accs[f], 0,0,0);
    accs[f] = __builtin_amdgcn_mfma_f32_16x16x32_bf16(aq1, bk1, accs[f], 0,0,0);
  }
  __syncthreads();   // sP bias staged

  const float scale = 0.14433756729740643f;  // 1/sqrt(48)
  #pragma unroll
  for(int f=0;f<16;f++){
    #pragma unroll
    for(int r=0;r<4;r++)
      accs[f][r] = accs[f][r]*scale + bf2f(sP[l4*4 + r][jbase + f*16 + l15]);
  }
  // ---- softmax (unnormalized) ----
  float pm[4];
  #pragma unroll
  for(int r=0;r<4;r++){
    float m = accs[0][r];
    #pragma unroll
    for(int f=1;f<16;f++) m = fmaxf(m, accs[f][r]);
    #pragma unroll
    for(int o=1;o<16;o<<=1) m = fmaxf(m, __shfl_xor(m, o));
    pm[r] = m;
  }
  if(l15 == 0){
    #pragma unroll
    for(int r=0;r<4;r++) sRedM[l4*4 + r][w] = pm[r];
  }
  __syncthreads();
  float rowm[4];
  #pragma unroll
  for(int r=0;r<4;r++){
    const int i = l4*4 + r;
    rowm[r] = fmaxf(fmaxf(sRedM[i][0], sRedM[i][1]), fmaxf(sRedM[i][2], sRedM[i][3]));
  }
  float psum[4] = {0.f,0.f,0.f,0.f};
  #pragma unroll
  for(int f=0;f<16;f++)
    #pragma unroll
    for(int r=0;r<4;r++){
      float p = __expf(accs[f][r] - rowm[r]);
      accs[f][r] = p;
      psum[r] += p;
    }
  #pragma unroll
  for(int r=0;r<4;r++)
    #pragma unroll
    for(int o=1;o<16;o<<=1) psum[r] += __shfl_xor(psum[r], o);
  if(l15 == 0){
    #pragma unroll
    for(int r=0;r<4;r++) sRedS[l4*4 + r][w] = psum[r];
  }
  #pragma unroll
  for(int f=0;f<16;f++)
    #pragma unroll
    for(int r=0;r<4;r++)
      sP[l4*4 + r][jbase + f*16 + l15] = f2bf(accs[f][r]);

  // ---- PV: B-frags straight from global VT (L2-hot) ----
  f32x4 acco[3];
  #pragma unroll
  for(int n=0;n<3;n++) acco[n] = zf;
  const unsigned short* vth = VT + ((long long)(h*48) << 10);
  #pragma unroll
  for(int c=0; c<4; c++){
    const int jb = jbase + c*64;
    #pragma unroll
    for(int kk=0; kk<2; kk++){
      bf16x8 pa = *(const bf16x8*)&sP[l15][jb + kk*32 + l4*8];
      #pragma unroll
      for(int n=0;n<3;n++){
        bf16x8 bv = *(const bf16x8*)&vth[((long long)(n*16 + l15) << 10) + jb + kk*32 + l4*8];
        acco[n] = __builtin_amdgcn_mfma_f32_16x16x32_bf16(pa, bv, acco[n], 0,0,0);
      }
    }
  }
  #pragma unroll
  for(int n=0;n<3;n++)
    #pragma unroll
    for(int r=0;r<4;r++)
      sO[w][l4*4 + r][n*16 + l15] = acco[n][r];
  __syncthreads();
  for(int t = tid; t < 768; t += 256){
    const int i = t / 48, d = t % 48;
    float o = sO[0][i][d] + sO[1][i][d] + sO[2][i][d] + sO[3][i][d];
    float lsum = sRedS[i][0] + sRedS[i][1] + sRedS[i][2] + sRedS[i][3];
    float gv = bf2f(GH[(long long)((h << 10) + i0 + i)*48 + d]);
    go[(long long)(i0 + i)*768 + h*48 + d] = f2bf(sigf(gv) * (o / lsum));
  }
}

// ---------------- finalA: out += gateA*(GO@W6), 4-way split-K -------------
__global__ __launch_bounds__(256) void finalA_kernel(
    const unsigned short* __restrict__ GO, const unsigned short* __restrict__ W6t,
    const float* __restrict__ gates, float* __restrict__ out){
  __shared__ __align__(16) unsigned short sA[128*32];
  __shared__ __align__(16) unsigned short sB[128*32];
  final_slice(GO, W6t, 768, blockIdx.z*192, blockIdx.z*192 + 192, 0,
              blockIdx.x*128, blockIdx.y*128, gates, out, sA, sB, threadIdx.x);
}

// ---------------------------------------------------------------------------
extern "C" void kernel_launch(void* const* d_in, const int* in_sizes, int n_in,
                              void* d_out, int out_size, void* d_ws, size_t ws_size,
                              hipStream_t stream){
  (void)in_sizes; (void)n_in; (void)out_size; (void)ws_size;
  const float* x    = (const float*)d_in[0];
  const float* sc   = (const float*)d_in[1];
  const float* pair = (const float*)d_in[2];
  const float* agw  = (const float*)d_in[3];
  const float* agb  = (const float*)d_in[4];
  const float* abw  = (const float*)d_in[5];
  const float* wq   = (const float*)d_in[6];
  const float* bq   = (const float*)d_in[7];
  const float* wk   = (const float*)d_in[8];
  const float* wv   = (const float*)d_in[9];
  const float* wb   = (const float*)d_in[10];
  const float* wg   = (const float*)d_in[11];
  const float* wo   = (const float*)d_in[12];
  const float* gtw  = (const float*)d_in[13];
  const float* gtb  = (const float*)d_in[14];
  const float* fgw  = (const float*)d_in[15];
  const float* fgb  = (const float*)d_in[16];
  const float* fbw  = (const float*)d_in[17];
  const float* fw1  = (const float*)d_in[18];
  const float* fw2  = (const float*)d_in[19];
  const float* fw3  = (const float*)d_in[20];
  const float* fgtw = (const float*)d_in[21];
  const float* fgtb = (const float*)d_in[22];
  float* out = (float*)d_out;
  char* ws = (char*)d_ws;

  unsigned short* SN   = (unsigned short*)(ws + OFF_SN);
  unsigned short* SC   = (unsigned short*)(ws + OFF_SC);
  float*          XA   = (float*)(ws + OFF_XA);
  unsigned short* W1   = (unsigned short*)(ws + OFF_W1);
  unsigned short* W2   = (unsigned short*)(ws + OFF_W2);
  unsigned short* W3   = (unsigned short*)(ws + OFF_W3);
  unsigned short* W4   = (unsigned short*)(ws + OFF_W4);
  unsigned short* W5   = (unsigned short*)(ws + OFF_W5);
  unsigned short* W6   = (unsigned short*)(ws + OFF_W6);
  float*          B1   = (float*)(ws + OFF_BIAS1);
  float*          BG   = (float*)(ws + OFF_BIASG);
  float*          BQ   = (float*)(ws + OFF_BIASQ);
  float*          G1   = (float*)(ws + OFF_G1);
  float*          GT   = (float*)(ws + OFF_GATES);
  unsigned short* A_   = (unsigned short*)(ws + OFF_A);
  unsigned short* F_   = (unsigned short*)(ws + OFF_F);
  unsigned short* QH   = (unsigned short*)(ws + OFF_QH);
  unsigned short* KH   = (unsigned short*)(ws + OFF_KH);
  unsigned short* GH   = (unsigned short*)(ws + OFF_GH);
  unsigned short* VT   = (unsigned short*)(ws + OFF_VT);
  unsigned short* HH   = (unsigned short*)(ws + OFF_HH);
  unsigned short* GO   = (unsigned short*)(ws + OFF_GO);
  unsigned short* PB   = (unsigned short*)(ws + OFF_PB);

  const unsigned long long W768 = 768ULL*768ULL*2ULL;

  // prep jobs: W1 (4) + W2 (2) -> 3456 tiles
  WJobs jobsP;
  {
    int ji = 0;
    auto setj = [&](const float* s, unsigned long long off, int K, int N,
                    int rm, int ro){
      jobsP.src[ji]=s; jobsP.dst[ji]=off; jobsP.K[ji]=K; jobsP.N[ji]=N;
      jobsP.rowmul[ji]=rm; jobsP.rowoff[ji]=ro; ji++;
    };
    setj(agw,  OFF_W1 + 0*W768, 768, 768, 1, 0);
    setj(abw,  OFF_W1 + 1*W768, 768, 768, 1, 0);
    setj(fgw,  OFF_W1 + 2*W768, 768, 768, 1, 0);
    setj(fbw,  OFF_W1 + 3*W768, 768, 768, 1, 0);
    setj(gtw,  OFF_W2 + 0*W768, 768, 768, 1, 0);
    setj(fgtw, OFF_W2 + 1*W768, 768, 768, 1, 0);
  }
  // fA jobs: W3 (4) + W4 (2, interleaved) + W5 + W6 -> 6336 tiles
  WJobs jobsA;
  {
    int ji = 0;
    auto setj = [&](const float* s, unsigned long long off, int K, int N,
                    int rm, int ro){
      jobsA.src[ji]=s; jobsA.dst[ji]=off; jobsA.K[ji]=K; jobsA.N[ji]=N;
      jobsA.rowmul[ji]=rm; jobsA.rowoff[ji]=ro; ji++;
    };
    setj(wq,   OFF_W3 + 0*W768, 768, 768, 1, 0);
    setj(wk,   OFF_W3 + 1*W768, 768, 768, 1, 0);
    setj(wv,   OFF_W3 + 2*W768, 768, 768, 1, 0);
    setj(wg,   OFF_W3 + 3*W768, 768, 768, 1, 0);
    setj(fw1,  OFF_W4, 768, 1536, 2, 0);   // interleaved: row 2c   = w1 col c
    setj(fw2,  OFF_W4, 768, 1536, 2, 1);   //              row 2c+1 = w2 col c
    setj(fw3,  OFF_W5, 1536, 768, 1, 0);
    setj(wo,   OFF_W6, 768, 768, 1, 0);
  }

  // prep: 3456 transpose + 1024 LN + 12 bias
  prep_kernel<<<4492, 256, 0, stream>>>(jobsP, ws, x, sc, SN, SC, XA,
      agb, bq, gtb, fgtb, fgb, B1, BG, BQ);
  // fA: G1+gates GEMMs (288) + W3..W6 transposes (6336) + pair [0,512) (2048)
  fA_kernel<<<8672, 256, 0, stream>>>(jobsA, ws, pair, wb, PB,
      SN, W1, B1, G1, SC, W2, BG, GT);
  // adaLN combine -> a, f (bf16); also out = x
  ew1_kernel<<<dim3(1024,3), 256, 0, stream>>>(G1, XA, A_, F_, x, out);
  // fB: QKVG(head-major)+HH GEMMs (384) + pair [512,1024) (2048)
  fB_kernel<<<2432, 256, 0, stream>>>(pair, wb, PB, A_, W3, BQ,
      QH, KH, GH, VT, F_, W4, HH);
  // attn (1024) + finalB HH@W5 (192, hidden under attn)
  attn_kernel<<<1216, 256, 0, stream>>>(QH, KH, GH, PB, VT, GO,
      HH, W5, GT, out);
  // finalA: out += gateA*(GO@wo)
  finalA_kernel<<<dim3(8,6,4), 256, 0, stream>>>(GO, W6, GT, out);
}

// Round 12
// 263.498 us; speedup vs baseline: 1.1581x; 1.0057x over previous
//
#include <hip/hip_runtime.h>
#include <hip/hip_bf16.h>

// ---------------------------------------------------------------------------
// DiffusionModule: AttentionPairBias + ConditionedFeedForward (AF3-style)
// B=1, N=1024, DS=768, DP=128, H=16, DH=48, DFF=1536. f32 in/out, bf16 MFMA.
// R12 = R11 + wave-autonomous LDS-staged pair stream:
//   coalesced global_load_lds (1KB/instr), per-wave vmcnt(0), NO barriers.
// ---------------------------------------------------------------------------

typedef __attribute__((ext_vector_type(8))) short bf16x8;
typedef __attribute__((ext_vector_type(4))) float f32x4;
typedef __attribute__((ext_vector_type(4))) unsigned short us4;

#define DEVFN static __device__ __forceinline__

DEVFN float bf2f(unsigned short u){
  union { unsigned int u; float f; } v; v.u = ((unsigned int)u) << 16; return v.f;
}
DEVFN unsigned short f2bf(float f){
  union { float f; unsigned int u; } v; v.f = f;
  unsigned int r = v.u + 0x7fffu + ((v.u >> 16) & 1u);
  return (unsigned short)(r >> 16);
}
DEVFN unsigned short f2bf_trunc(float f){
  union { float f; unsigned int u; } v; v.f = f;
  return (unsigned short)(v.u >> 16);
}
DEVFN float sigf(float x){ return 1.f / (1.f + __expf(-x)); }

DEVFN void gload16(const void* g, void* l){
  __builtin_amdgcn_global_load_lds(
      (const __attribute__((address_space(1))) void*)g,
      (__attribute__((address_space(3))) void*)l, 16, 0, 0);
}

// ---------------- workspace layout (bytes) ----------------
#define OFF_SN    0x0000000ULL
#define OFF_SC    0x0180000ULL
#define OFF_XA    0x0300000ULL
#define OFF_W1    0x0600000ULL
#define OFF_W2    0x0A80000ULL
#define OFF_W3    0x0CC0000ULL
#define OFF_W4    0x1140000ULL
#define OFF_W5    0x15C0000ULL
#define OFF_W6    0x1800000ULL
#define OFF_BIAS1 0x1920000ULL
#define OFF_BIASG 0x1923000ULL
#define OFF_BIASQ 0x1924800ULL
#define OFF_G1    0x1930000ULL
#define OFF_GATES 0x2530000ULL
#define OFF_A     0x2B30000ULL
#define OFF_F     0x2CB0000ULL
#define OFF_QH    0x2E30000ULL
#define OFF_KH    0x2FB0000ULL
#define OFF_GH    0x3130000ULL
#define OFF_VT    0x3430000ULL
#define OFF_HH    0x4030000ULL
#define OFF_GO    0x4330000ULL
#define OFF_PB    0x47B0000ULL

struct WJobs {
  const float* src[8];
  unsigned long long dst[8];
  int K[8];
  int N[8];
  int rowmul[8];
  int rowoff[8];
};

// ---------------- transpose tile: dst[n*rm+ro][k] = bf16(src[k][n]) --------
DEVFN void transpose_tile(const WJobs& jobs, char* ws, int t, int tid, void* smem){
  int z = 0;
  while(true){
    int nt = (jobs.N[z] >> 5) * (jobs.K[z] >> 5);
    if(t < nt) break;
    t -= nt; z++;
  }
  const int nx = jobs.N[z] >> 5;
  const int n0 = (t % nx) << 5, k0 = (t / nx) << 5;
  const int K = jobs.K[z], N = jobs.N[z];
  float (*tt)[33] = (float(*)[33])smem;
  const int tx = tid & 31, ty = tid >> 5;
  const float* src = jobs.src[z];
  #pragma unroll
  for(int i=0;i<4;i++)
    tt[ty + i*8][tx] = src[(long long)(k0 + ty + i*8) * N + n0 + tx];
  __syncthreads();
  unsigned short* dst = (unsigned short*)(ws + jobs.dst[z]);
  const int rm = jobs.rowmul[z], ro = jobs.rowoff[z];
  #pragma unroll
  for(int i=0;i<4;i++)
    dst[(long long)((n0 + ty + i*8)*rm + ro) * K + k0 + tx] = f2bf(tt[tx][ty + i*8]);
}

// ---------------- prep: W1/W2 transpose + LN rows + bias build -------------
// grid 4492: [0,3456) transpose, [3456,4480) LN, [4480,4492) bias.
__global__ __launch_bounds__(256) void prep_kernel(WJobs jobsP, char* ws,
    const float* __restrict__ x, const float* __restrict__ sc,
    unsigned short* __restrict__ sn_bf, unsigned short* __restrict__ sc_bf,
    float* __restrict__ xa,
    const float* agb, const float* bq, const float* gtb, const float* fgtb,
    const float* fgb, float* bias1, float* biasg, float* biasq){
  __shared__ __align__(16) char smem[4352];
  const int bid = blockIdx.x;
  const int tid = threadIdx.x;
  if(bid < 3456){
    transpose_tile(jobsP, ws, bid, tid, smem);
    return;
  }
  if(bid >= 4480){
    int t = (bid - 4480) * 256 + tid;
    float v = 0.f;
    if(t < 768) v = agb[t];
    else if(t >= 1536 && t < 2304) v = fgb[t - 1536];
    bias1[t] = v;
    biasq[t] = (t < 768) ? bq[t] : 0.f;
    if(t < 1536) biasg[t] = (t < 768) ? gtb[t] : fgtb[t - 768];
    return;
  }
  // ---- LN row ----
  const int row = bid - 3456;
  const float* xr = x + (long long)row * 768;
  const float* sr = sc + (long long)row * 768;
  float xs[3], ss[3];
  float s0=0.f, s1=0.f, s2=0.f, s3=0.f;
  #pragma unroll
  for(int i=0;i<3;i++){
    float xv = xr[tid + i*256], sv = sr[tid + i*256];
    xs[i]=xv; ss[i]=sv;
    s0 += xv; s1 += xv*xv; s2 += sv; s3 += sv*sv;
  }
  #pragma unroll
  for(int o=32;o;o>>=1){
    s0 += __shfl_xor(s0,o); s1 += __shfl_xor(s1,o);
    s2 += __shfl_xor(s2,o); s3 += __shfl_xor(s3,o);
  }
  float (*red)[4] = (float(*)[4])smem;
  const int w = tid >> 6;
  if((tid & 63) == 0){ red[0][w]=s0; red[1][w]=s1; red[2][w]=s2; red[3][w]=s3; }
  __syncthreads();
  float tx0 = red[0][0]+red[0][1]+red[0][2]+red[0][3];
  float tx1 = red[1][0]+red[1][1]+red[1][2]+red[1][3];
  float ts0 = red[2][0]+red[2][1]+red[2][2]+red[2][3];
  float ts1 = red[3][0]+red[3][1]+red[3][2]+red[3][3];
  const float inv = 1.f/768.f;
  float mx = tx0*inv, vx = tx1*inv - mx*mx;
  float ms = ts0*inv, vs = ts1*inv - ms*ms;
  float rsx = rsqrtf(vx + 1e-5f), rss = rsqrtf(vs + 1e-5f);
  #pragma unroll
  for(int i=0;i<3;i++){
    int c = tid + i*256;
    xa[(long long)row*768 + c]    = (xs[i]-mx)*rsx;
    sn_bf[(long long)row*768 + c] = f2bf((ss[i]-ms)*rss);
    sc_bf[(long long)row*768 + c] = f2bf(ss[i]);
  }
}

// ---------------- shared GEMM tile body (128x128, BK=32, gload_lds) --------
DEVFN void gemm_tile_f32(const unsigned short* __restrict__ A,
                         const unsigned short* __restrict__ Bt,
                         int N, int K, int m0, int n0,
                         const float* __restrict__ bias,
                         float* __restrict__ Cf, int epi,
                         unsigned short* sA, unsigned short* sB, int tid){
  const int w = tid >> 6, l = tid & 63, l15 = l & 15, l4 = l >> 4;
  const int wm = w >> 1, wn = w & 1;
  f32x4 zf = {0.f,0.f,0.f,0.f};
  f32x4 acc[4][4];
  #pragma unroll
  for(int m=0;m<4;m++)
    #pragma unroll
    for(int n=0;n<4;n++) acc[m][n] = zf;

  const int srow = w*16 + (l >> 2);
  const int scol = (l & 3) * 8;
  const unsigned short* gA = A  + (long long)(m0 + srow) * K + scol;
  const unsigned short* gB = Bt + (long long)(n0 + srow) * K + scol;
  unsigned short* lA0 = &sA[(w*16)*32];
  unsigned short* lA1 = &sA[(64 + w*16)*32];
  unsigned short* lB0 = &sB[(w*16)*32];
  unsigned short* lB1 = &sB[(64 + w*16)*32];
  const long long half = (long long)64 * K;

  for(int k0 = 0; k0 < K; k0 += 32){
    gload16(gA + k0, lA0);
    gload16(gA + half + k0, lA1);
    gload16(gB + k0, lB0);
    gload16(gB + half + k0, lB1);
    __syncthreads();
    bf16x8 af[4], bg[4];
    #pragma unroll
    for(int m=0;m<4;m++) af[m] = *(const bf16x8*)&sA[(wm*64 + m*16 + l15)*32 + l4*8];
    #pragma unroll
    for(int n=0;n<4;n++) bg[n] = *(const bf16x8*)&sB[(wn*64 + n*16 + l15)*32 + l4*8];
    #pragma unroll
    for(int m=0;m<4;m++)
      #pragma unroll
      for(int n=0;n<4;n++)
        acc[m][n] = __builtin_amdgcn_mfma_f32_16x16x32_bf16(af[m], bg[n], acc[m][n], 0, 0, 0);
    __syncthreads();
  }
  #pragma unroll
  for(int m=0;m<4;m++){
    #pragma unroll
    for(int n=0;n<4;n++){
      #pragma unroll
      for(int r=0;r<4;r++){
        const int i = m0 + wm*64 + m*16 + l4*4 + r;
        const int c = n0 + wn*64 + n*16 + l15;
        float v = acc[m][n][r] + bias[c];
        Cf[(long long)i*N + c] = epi ? sigf(v) : v;
      }
    }
  }
}

// ---------------- pair-bias block: wave-autonomous LDS staging -------------
// Block covers 256 rows; per q, each wave stages its OWN 16 rows (8 KB) via
// 8 coalesced global_load_lds (1 KB each, inverse-XOR-swizzled source), then
// per-wave s_waitcnt vmcnt(0) -- NO __syncthreads in this path.
DEVFN void pair_block(int pbid, const float* __restrict__ pair,
                      const float* __restrict__ wb,
                      unsigned short* __restrict__ pb, int tid, char* lds){
  const int l = tid & 63, w = tid >> 6, l15 = l & 15, l4 = l >> 4;
  bf16x8 wbf[4];
  #pragma unroll
  for(int c=0;c<4;c++){
    bf16x8 t;
    #pragma unroll
    for(int e=0;e<8;e++) t[e] = (short)f2bf(wb[(c*32 + l4*8 + e)*16 + l15]);
    wbf[c] = t;
  }
  const long long blockrow0 = (long long)pbid * 256;
  char* wlds = lds + w*8192;
  const int lane16 = (l & 31) * 16;   // byte col within row, pre-swizzle
  const int lhi = l >> 5;             // 0/1: which of 2 rows per issue
  const int swr = l15 << 4;           // read-side swizzle for this lane's row

  for(int q=0;q<4;q++){
    const char* gbase = (const char*)pair + ((blockrow0 + (long long)(q*64)) << 9);
    #pragma unroll
    for(int is=0; is<8; is++){
      const int r = w*16 + is*2 + lhi;            // staged row 0..63
      gload16(gbase + ((long long)r << 9) + (lane16 ^ ((r & 15) << 4)),
              wlds + is*1024);
    }
    asm volatile("s_waitcnt vmcnt(0)" ::: "memory");
    __builtin_amdgcn_sched_barrier(0);
    // ---- read (swizzled) + LN + MFMA ----
    const char* rowp = wlds + l15*512;
    float vals[32];
    #pragma unroll
    for(int c=0;c<4;c++){
      const int x = c*128 + l4*32;
      float4 v0 = *(const float4*)(rowp + (x ^ swr));
      float4 v1 = *(const float4*)(rowp + ((x + 16) ^ swr));
      vals[c*8+0]=v0.x; vals[c*8+1]=v0.y; vals[c*8+2]=v0.z; vals[c*8+3]=v0.w;
      vals[c*8+4]=v1.x; vals[c*8+5]=v1.y; vals[c*8+6]=v1.z; vals[c*8+7]=v1.w;
    }
    float s=0.f, s2=0.f;
    #pragma unroll
    for(int e=0;e<32;e++){ s += vals[e]; s2 += vals[e]*vals[e]; }
    s += __shfl_xor(s, 16); s2 += __shfl_xor(s2, 16);
    s += __shfl_xor(s, 32); s2 += __shfl_xor(s2, 32);
    const float m = s * (1.f/128.f);
    const float rs = rsqrtf(s2*(1.f/128.f) - m*m + 1e-5f);
    f32x4 acc = {0.f,0.f,0.f,0.f};
    #pragma unroll
    for(int c=0;c<4;c++){
      bf16x8 af;
      #pragma unroll
      for(int e=0;e<8;e++) af[e] = (short)f2bf_trunc((vals[c*8+e] - m) * rs);
      acc = __builtin_amdgcn_mfma_f32_16x16x32_bf16(af, wbf[c], acc, 0,0,0);
    }
    const long long row0 = blockrow0 + q*64 + w*16;
    us4 o;
    #pragma unroll
    for(int r=0;r<4;r++) o[r] = f2bf(acc[r]);
    *(us4*)&pb[((long long)l15 << 20) + row0 + l4*4] = o;
    // drain this wave's LDS reads before next q's staging overwrites
    asm volatile("s_waitcnt lgkmcnt(0)" ::: "memory");
    __builtin_amdgcn_sched_barrier(0);
  }
}

// ---------------- fA: G1+gates GEMMs + W3..W6 transposes + pair [0,512) ----
// grid 8672: [0,288) GEMM, [288,6624) transpose (jobsA), [6624,8672) pair.
__global__ __launch_bounds__(256) void fA_kernel(
    WJobs jobsA, char* ws,
    const float* __restrict__ pair, const float* __restrict__ wb,
    unsigned short* __restrict__ pb,
    const unsigned short* __restrict__ SN, const unsigned short* __restrict__ W1,
    const float* __restrict__ B1, float* __restrict__ G1,
    const unsigned short* __restrict__ SC, const unsigned short* __restrict__ W2,
    const float* __restrict__ BG, float* __restrict__ GT){
  __shared__ __align__(16) unsigned short smem[16384];   // 32 KB
  const int bid = blockIdx.x;
  const int tid = threadIdx.x;
  if(bid < 288){
    if(bid < 192){
      gemm_tile_f32(SN, W1, 3072, 768, (bid & 7)*128, (bid >> 3)*128, B1, G1, 0,
                    smem, smem + 4096, tid);
    } else {
      const int t = bid - 192;
      gemm_tile_f32(SC, W2, 1536, 768, (t & 7)*128, (t >> 3)*128, BG, GT, 1,
                    smem, smem + 4096, tid);
    }
    return;
  }
  if(bid < 6624){
    transpose_tile(jobsA, ws, bid - 288, tid, smem);
    return;
  }
  pair_block(bid - 6624, pair, wb, pb, tid, (char*)smem);
}

// ---------------- elementwise: adaLN combine + out=x init ----------------
__global__ __launch_bounds__(256) void ew1_kernel(const float* __restrict__ g1,
    const float* __restrict__ xa, unsigned short* __restrict__ a_bf,
    unsigned short* __restrict__ f_bf, const float* __restrict__ x,
    float* __restrict__ out){
  const int i = blockIdx.x;
  const int c = blockIdx.y * 256 + threadIdx.x;
  const float* row = g1 + (long long)i * 3072;
  float xv = xa[(long long)i*768 + c];
  a_bf[(long long)i*768 + c] = f2bf(sigf(row[c])      * xv + row[768 + c]);
  f_bf[(long long)i*768 + c] = f2bf(sigf(row[1536+c]) * xv + row[2304 + c]);
  out[(long long)i*768 + c] = x[(long long)i*768 + c];
}

// ---------------- fB: QKVG GEMM (head-major out) + HH GEMM + pair ----------
__global__ __launch_bounds__(256) void fB_kernel(
    const float* __restrict__ pair, const float* __restrict__ wb,
    unsigned short* __restrict__ pb,
    const unsigned short* __restrict__ A_, const unsigned short* __restrict__ W3,
    const float* __restrict__ BQ,
    unsigned short* __restrict__ QH, unsigned short* __restrict__ KH,
    unsigned short* __restrict__ GH, unsigned short* __restrict__ VT,
    const unsigned short* __restrict__ F_, const unsigned short* __restrict__ W4,
    unsigned short* __restrict__ HH){
  __shared__ __align__(16) unsigned short smem[16384];   // 32 KB
  const int bid = blockIdx.x;
  const int tid = threadIdx.x;
  if(bid >= 384){
    pair_block(bid - 384 + 2048, pair, wb, pb, tid, (char*)smem);
    return;
  }
  unsigned short* sA = smem;
  unsigned short* sB = smem + 4096;
  const bool isq = bid < 192;
  const int t = isq ? bid : bid - 192;
  const int m0 = (t & 7) * 128, n0 = (t >> 3) * 128;
  const unsigned short* A  = isq ? A_ : F_;
  const unsigned short* Bt = isq ? W3 : W4;
  const int K = 768;

  const int w = tid >> 6, l = tid & 63, l15 = l & 15, l4 = l >> 4;
  const int wm = w >> 1, wn = w & 1;
  f32x4 zf = {0.f,0.f,0.f,0.f};
  f32x4 acc[4][4];
  #pragma unroll
  for(int m=0;m<4;m++)
    #pragma unroll
    for(int n=0;n<4;n++) acc[m][n] = zf;

  const int srow = w*16 + (l >> 2);
  const int scol = (l & 3) * 8;
  const unsigned short* gA = A  + (long long)(m0 + srow) * K + scol;
  const unsigned short* gB = Bt + (long long)(n0 + srow) * K + scol;
  unsigned short* lA0 = &sA[(w*16)*32];
  unsigned short* lA1 = &sA[(64 + w*16)*32];
  unsigned short* lB0 = &sB[(w*16)*32];
  unsigned short* lB1 = &sB[(64 + w*16)*32];
  const long long half = (long long)64 * K;

  for(int k0 = 0; k0 < K; k0 += 32){
    gload16(gA + k0, lA0);
    gload16(gA + half + k0, lA1);
    gload16(gB + k0, lB0);
    gload16(gB + half + k0, lB1);
    __syncthreads();
    bf16x8 af[4], bg[4];
    #pragma unroll
    for(int m=0;m<4;m++) af[m] = *(const bf16x8*)&sA[(wm*64 + m*16 + l15)*32 + l4*8];
    #pragma unroll
    for(int n=0;n<4;n++) bg[n] = *(const bf16x8*)&sB[(wn*64 + n*16 + l15)*32 + l4*8];
    #pragma unroll
    for(int m=0;m<4;m++)
      #pragma unroll
      for(int n=0;n<4;n++)
        acc[m][n] = __builtin_amdgcn_mfma_f32_16x16x32_bf16(af[m], bg[n], acc[m][n], 0, 0, 0);
    __syncthreads();
  }
  if(isq){
    #pragma unroll
    for(int m=0;m<4;m++){
      #pragma unroll
      for(int n=0;n<4;n++){
        const int c = n0 + wn*64 + n*16 + l15;
        const int ibase = m0 + wm*64 + m*16 + l4*4;
        const int which = c / 768;           // 0=q 1=k 2=v 3=g
        const int h = (c % 768) / 48, d = c % 48;
        unsigned short vb[4];
        #pragma unroll
        for(int r=0;r<4;r++) vb[r] = f2bf(acc[m][n][r] + BQ[c]);
        if(which == 2){
          us4 o; o.x=vb[0]; o.y=vb[1]; o.z=vb[2]; o.w=vb[3];
          *(us4*)&VT[((long long)(c - 1536) << 10) + ibase] = o;
        } else {
          unsigned short* dst = (which == 0) ? QH : (which == 1) ? KH : GH;
          #pragma unroll
          for(int r=0;r<4;r++)
            dst[((long long)((h << 10) + ibase + r))*48 + d] = vb[r];
        }
      }
    }
  } else {
    #pragma unroll
    for(int m=0;m<4;m++){
      #pragma unroll
      for(int n=0;n<4;n++){
        #pragma unroll
        for(int r=0;r<4;r++){
          const int i = m0 + wm*64 + m*16 + l4*4 + r;
          const int c = n0 + wn*64 + n*16 + l15;
          float v = acc[m][n][r];
          float partner = __shfl_xor(v, 1);
          if((c & 1) == 0)
            HH[(long long)i*1536 + (c>>1)] = f2bf(v * sigf(v) * partner);
        }
      }
    }
  }
}

// ---------------- final GEMM-slice body (split-K atomics into out) ---------
DEVFN void final_slice(const unsigned short* __restrict__ A,
                       const unsigned short* __restrict__ Bt,
                       int K, int kbeg, int kend, int goff, int m0, int n0,
                       const float* __restrict__ gates, float* __restrict__ out,
                       unsigned short* sA, unsigned short* sB, int tid){
  const int w = tid >> 6, l = tid & 63, l15 = l & 15, l4 = l >> 4;
  const int wm = w >> 1, wn = w & 1;
  f32x4 zf = {0.f,0.f,0.f,0.f};
  f32x4 acc[4][4];
  #pragma unroll
  for(int m=0;m<4;m++)
    #pragma unroll
    for(int n=0;n<4;n++) acc[m][n] = zf;

  const int srow = w*16 + (l >> 2);
  const int scol = (l & 3) * 8;
  const unsigned short* gA = A  + (long long)(m0 + srow) * K + scol;
  const unsigned short* gB = Bt + (long long)(n0 + srow) * K + scol;
  unsigned short* lA0 = &sA[(w*16)*32];
  unsigned short* lA1 = &sA[(64 + w*16)*32];
  unsigned short* lB0 = &sB[(w*16)*32];
  unsigned short* lB1 = &sB[(64 + w*16)*32];
  const long long half = (long long)64 * K;

  for(int k0 = kbeg; k0 < kend; k0 += 32){
    gload16(gA + k0, lA0);
    gload16(gA + half + k0, lA1);
    gload16(gB + k0, lB0);
    gload16(gB + half + k0, lB1);
    __syncthreads();
    bf16x8 af[4], bg[4];
    #pragma unroll
    for(int m=0;m<4;m++) af[m] = *(const bf16x8*)&sA[(wm*64 + m*16 + l15)*32 + l4*8];
    #pragma unroll
    for(int n=0;n<4;n++) bg[n] = *(const bf16x8*)&sB[(wn*64 + n*16 + l15)*32 + l4*8];
    #pragma unroll
    for(int m=0;m<4;m++)
      #pragma unroll
      for(int n=0;n<4;n++)
        acc[m][n] = __builtin_amdgcn_mfma_f32_16x16x32_bf16(af[m], bg[n], acc[m][n], 0, 0, 0);
    __syncthreads();
  }
  #pragma unroll
  for(int m=0;m<4;m++){
    #pragma unroll
    for(int n=0;n<4;n++){
      #pragma unroll
      for(int r=0;r<4;r++){
        const int i = m0 + wm*64 + m*16 + l4*4 + r;
        const int c = n0 + wn*64 + n*16 + l15;
        float v = gates[(long long)i*1536 + goff + c] * acc[m][n][r];
        __hip_atomic_fetch_add(&out[(long long)i*768 + c], v,
                               __ATOMIC_RELAXED, __HIP_MEMORY_SCOPE_AGENT);
      }
    }
  }
}

// ---------------- attn launch: [0,192) finalB (HH@W5) + [192,1216) attn ----
__global__ __launch_bounds__(256) void attn_kernel(
    const unsigned short* __restrict__ QH, const unsigned short* __restrict__ KH,
    const unsigned short* __restrict__ GH,
    const unsigned short* __restrict__ pbias,
    const unsigned short* __restrict__ VT,
    unsigned short* __restrict__ go,
    const unsigned short* __restrict__ HH, const unsigned short* __restrict__ W5t,
    const float* __restrict__ gates, float* __restrict__ out){
  __shared__ __align__(16) char smem[45824];
  const int bid = blockIdx.x;
  const int tid = threadIdx.x;
  if(bid < 192){
    const int z = bid / 48, rem = bid % 48;
    final_slice(HH, W5t, 1536, z*384, z*384 + 384, 768,
                (rem & 7)*128, (rem >> 3)*128, gates, out,
                (unsigned short*)smem, (unsigned short*)(smem + 8192), tid);
    return;
  }
  const int it = bid - 192;
  const int h  = it >> 6;
  const int i0 = (it & 63) << 4;
  const int w = tid >> 6, l = tid & 63, l15 = l & 15, l4 = l >> 4;

  unsigned short (*sP)[1032] = (unsigned short(*)[1032])smem;      // 33024
  float (*sRedM)[4] = (float(*)[4])(smem + 33024);                 // 256
  float (*sRedS)[4] = (float(*)[4])(smem + 33280);                 // 256
  float (*sO)[16][48] = (float(*)[16][48])(smem + 33536);          // 12288

  f32x4 zf = {0.f,0.f,0.f,0.f};
  bf16x8 zero8 = {0,0,0,0,0,0,0,0};

  const unsigned short* pbh = pbias + ((long long)h << 20) + ((long long)i0 << 10);
  #pragma unroll
  for(int itr=0; itr<8; itr++){
    const int idx = itr*2048 + tid*8;
    const int r = idx >> 10, c = idx & 1023;
    *(bf16x8*)&sP[r][c] = *(const bf16x8*)&pbh[((long long)r << 10) + c];
  }

  // ---- QK^T ----
  f32x4 accs[16];
  #pragma unroll
  for(int f=0;f<16;f++) accs[f] = zf;
  bf16x8 aq0, aq1;
  {
    const unsigned short* qp = QH + (long long)((h << 10) + i0 + l15)*48;
    aq0 = *(const bf16x8*)(qp + l4*8);
    aq1 = *(const bf16x8*)(qp + 32 + l4*8);
  }
  const int jbase = w * 256;
  #pragma unroll
  for(int f=0; f<16; f++){
    const int j = jbase + f*16 + l15;
    const unsigned short* kp = KH + (long long)((h << 10) + j)*48;
    bf16x8 bk0 = *(const bf16x8*)(kp + l4*8);
    bf16x8 bk1 = *(const bf16x8*)(kp + 32 + l4*8);
    if(l4 >= 2) bk1 = zero8;
    accs[f] = __builtin_amdgcn_mfma_f32_16x16x32_bf16(aq0, bk0, accs[f], 0,0,0);
    accs[f] = __builtin_amdgcn_mfma_f32_16x16x32_bf16(aq1, bk1, accs[f], 0,0,0);
  }
  __syncthreads();   // sP bias staged

  const float scale = 0.14433756729740643f;  // 1/sqrt(48)
  #pragma unroll
  for(int f=0;f<16;f++){
    #pragma unroll
    for(int r=0;r<4;r++)
      accs[f][r] = accs[f][r]*scale + bf2f(sP[l4*4 + r][jbase + f*16 + l15]);
  }
  // ---- softmax (unnormalized) ----
  float pm[4];
  #pragma unroll
  for(int r=0;r<4;r++){
    float m = accs[0][r];
    #pragma unroll
    for(int f=1;f<16;f++) m = fmaxf(m, accs[f][r]);
    #pragma unroll
    for(int o=1;o<16;o<<=1) m = fmaxf(m, __shfl_xor(m, o));
    pm[r] = m;
  }
  if(l15 == 0){
    #pragma unroll
    for(int r=0;r<4;r++) sRedM[l4*4 + r][w] = pm[r];
  }
  __syncthreads();
  float rowm[4];
  #pragma unroll
  for(int r=0;r<4;r++){
    const int i = l4*4 + r;
    rowm[r] = fmaxf(fmaxf(sRedM[i][0], sRedM[i][1]), fmaxf(sRedM[i][2], sRedM[i][3]));
  }
  float psum[4] = {0.f,0.f,0.f,0.f};
  #pragma unroll
  for(int f=0;f<16;f++)
    #pragma unroll
    for(int r=0;r<4;r++){
      float p = __expf(accs[f][r] - rowm[r]);
      accs[f][r] = p;
      psum[r] += p;
    }
  #pragma unroll
  for(int r=0;r<4;r++)
    #pragma unroll
    for(int o=1;o<16;o<<=1) psum[r] += __shfl_xor(psum[r], o);
  if(l15 == 0){
    #pragma unroll
    for(int r=0;r<4;r++) sRedS[l4*4 + r][w] = psum[r];
  }
  #pragma unroll
  for(int f=0;f<16;f++)
    #pragma unroll
    for(int r=0;r<4;r++)
      sP[l4*4 + r][jbase + f*16 + l15] = f2bf(accs[f][r]);

  // ---- PV: B-frags straight from global VT (L2-hot) ----
  f32x4 acco[3];
  #pragma unroll
  for(int n=0;n<3;n++) acco[n] = zf;
  const unsigned short* vth = VT + ((long long)(h*48) << 10);
  #pragma unroll
  for(int c=0; c<4; c++){
    const int jb = jbase + c*64;
    #pragma unroll
    for(int kk=0; kk<2; kk++){
      bf16x8 pa = *(const bf16x8*)&sP[l15][jb + kk*32 + l4*8];
      #pragma unroll
      for(int n=0;n<3;n++){
        bf16x8 bv = *(const bf16x8*)&vth[((long long)(n*16 + l15) << 10) + jb + kk*32 + l4*8];
        acco[n] = __builtin_amdgcn_mfma_f32_16x16x32_bf16(pa, bv, acco[n], 0,0,0);
      }
    }
  }
  #pragma unroll
  for(int n=0;n<3;n++)
    #pragma unroll
    for(int r=0;r<4;r++)
      sO[w][l4*4 + r][n*16 + l15] = acco[n][r];
  __syncthreads();
  for(int t = tid; t < 768; t += 256){
    const int i = t / 48, d = t % 48;
    float o = sO[0][i][d] + sO[1][i][d] + sO[2][i][d] + sO[3][i][d];
    float lsum = sRedS[i][0] + sRedS[i][1] + sRedS[i][2] + sRedS[i][3];
    float gv = bf2f(GH[(long long)((h << 10) + i0 + i)*48 + d]);
    go[(long long)(i0 + i)*768 + h*48 + d] = f2bf(sigf(gv) * (o / lsum));
  }
}

// ---------------- finalA: out += gateA*(GO@W6), 4-way split-K -------------
__global__ __launch_bounds__(256) void finalA_kernel(
    const unsigned short* __restrict__ GO, const unsigned short* __restrict__ W6t,
    const float* __restrict__ gates, float* __restrict__ out){
  __shared__ __align__(16) unsigned short sA[128*32];
  __shared__ __align__(16) unsigned short sB[128*32];
  final_slice(GO, W6t, 768, blockIdx.z*192, blockIdx.z*192 + 192, 0,
              blockIdx.x*128, blockIdx.y*128, gates, out, sA, sB, threadIdx.x);
}

// ---------------------------------------------------------------------------
extern "C" void kernel_launch(void* const* d_in, const int* in_sizes, int n_in,
                              void* d_out, int out_size, void* d_ws, size_t ws_size,
                              hipStream_t stream){
  (void)in_sizes; (void)n_in; (void)out_size; (void)ws_size;
  const float* x    = (const float*)d_in[0];
  const float* sc   = (const float*)d_in[1];
  const float* pair = (const float*)d_in[2];
  const float* agw  = (const float*)d_in[3];
  const float* agb  = (const float*)d_in[4];
  const float* abw  = (const float*)d_in[5];
  const float* wq   = (const float*)d_in[6];
  const float* bq   = (const float*)d_in[7];
  const float* wk   = (const float*)d_in[8];
  const float* wv   = (const float*)d_in[9];
  const float* wb   = (const float*)d_in[10];
  const float* wg   = (const float*)d_in[11];
  const float* wo   = (const float*)d_in[12];
  const float* gtw  = (const float*)d_in[13];
  const float* gtb  = (const float*)d_in[14];
  const float* fgw  = (const float*)d_in[15];
  const float* fgb  = (const float*)d_in[16];
  const float* fbw  = (const float*)d_in[17];
  const float* fw1  = (const float*)d_in[18];
  const float* fw2  = (const float*)d_in[19];
  const float* fw3  = (const float*)d_in[20];
  const float* fgtw = (const float*)d_in[21];
  const float* fgtb = (const float*)d_in[22];
  float* out = (float*)d_out;
  char* ws = (char*)d_ws;

  unsigned short* SN   = (unsigned short*)(ws + OFF_SN);
  unsigned short* SC   = (unsigned short*)(ws + OFF_SC);
  float*          XA   = (float*)(ws + OFF_XA);
  unsigned short* W1   = (unsigned short*)(ws + OFF_W1);
  unsigned short* W2   = (unsigned short*)(ws + OFF_W2);
  unsigned short* W3   = (unsigned short*)(ws + OFF_W3);
  unsigned short* W4   = (unsigned short*)(ws + OFF_W4);
  unsigned short* W5   = (unsigned short*)(ws + OFF_W5);
  unsigned short* W6   = (unsigned short*)(ws + OFF_W6);
  float*          B1   = (float*)(ws + OFF_BIAS1);
  float*          BG   = (float*)(ws + OFF_BIASG);
  float*          BQ   = (float*)(ws + OFF_BIASQ);
  float*          G1   = (float*)(ws + OFF_G1);
  float*          GT   = (float*)(ws + OFF_GATES);
  unsigned short* A_   = (unsigned short*)(ws + OFF_A);
  unsigned short* F_   = (unsigned short*)(ws + OFF_F);
  unsigned short* QH   = (unsigned short*)(ws + OFF_QH);
  unsigned short* KH   = (unsigned short*)(ws + OFF_KH);
  unsigned short* GH   = (unsigned short*)(ws + OFF_GH);
  unsigned short* VT   = (unsigned short*)(ws + OFF_VT);
  unsigned short* HH   = (unsigned short*)(ws + OFF_HH);
  unsigned short* GO   = (unsigned short*)(ws + OFF_GO);
  unsigned short* PB   = (unsigned short*)(ws + OFF_PB);

  const unsigned long long W768 = 768ULL*768ULL*2ULL;

  WJobs jobsP;
  {
    int ji = 0;
    auto setj = [&](const float* s, unsigned long long off, int K, int N,
                    int rm, int ro){
      jobsP.src[ji]=s; jobsP.dst[ji]=off; jobsP.K[ji]=K; jobsP.N[ji]=N;
      jobsP.rowmul[ji]=rm; jobsP.rowoff[ji]=ro; ji++;
    };
    setj(agw,  OFF_W1 + 0*W768, 768, 768, 1, 0);
    setj(abw,  OFF_W1 + 1*W768, 768, 768, 1, 0);
    setj(fgw,  OFF_W1 + 2*W768, 768, 768, 1, 0);
    setj(fbw,  OFF_W1 + 3*W768, 768, 768, 1, 0);
    setj(gtw,  OFF_W2 + 0*W768, 768, 768, 1, 0);
    setj(fgtw, OFF_W2 + 1*W768, 768, 768, 1, 0);
  }
  WJobs jobsA;
  {
    int ji = 0;
    auto setj = [&](const float* s, unsigned long long off, int K, int N,
                    int rm, int ro){
      jobsA.src[ji]=s; jobsA.dst[ji]=off; jobsA.K[ji]=K; jobsA.N[ji]=N;
      jobsA.rowmul[ji]=rm; jobsA.rowoff[ji]=ro; ji++;
    };
    setj(wq,   OFF_W3 + 0*W768, 768, 768, 1, 0);
    setj(wk,   OFF_W3 + 1*W768, 768, 768, 1, 0);
    setj(wv,   OFF_W3 + 2*W768, 768, 768, 1, 0);
    setj(wg,   OFF_W3 + 3*W768, 768, 768, 1, 0);
    setj(fw1,  OFF_W4, 768, 1536, 2, 0);
    setj(fw2,  OFF_W4, 768, 1536, 2, 1);
    setj(fw3,  OFF_W5, 1536, 768, 1, 0);
    setj(wo,   OFF_W6, 768, 768, 1, 0);
  }

  prep_kernel<<<4492, 256, 0, stream>>>(jobsP, ws, x, sc, SN, SC, XA,
      agb, bq, gtb, fgtb, fgb, B1, BG, BQ);
  fA_kernel<<<8672, 256, 0, stream>>>(jobsA, ws, pair, wb, PB,
      SN, W1, B1, G1, SC, W2, BG, GT);
  ew1_kernel<<<dim3(1024,3), 256, 0, stream>>>(G1, XA, A_, F_, x, out);
  fB_kernel<<<2432, 256, 0, stream>>>(pair, wb, PB, A_, W3, BQ,
      QH, KH, GH, VT, F_, W4, HH);
  attn_kernel<<<1216, 256, 0, stream>>>(QH, KH, GH, PB, VT, GO,
      HH, W5, GT, out);
  finalA_kernel<<<dim3(8,6,4), 256, 0, stream>>>(GO, W6, GT, out);
}

// Round 13
// 260.321 us; speedup vs baseline: 1.1722x; 1.0122x over previous
//
#include <hip/hip_runtime.h>
#include <hip/hip_bf16.h>

// ---------------------------------------------------------------------------
// DiffusionModule: AttentionPairBias + ConditionedFeedForward (AF3-style)
// B=1, N=1024, DS=768, DP=128, H=16, DH=48, DFF=1536. f32 in/out, bf16 MFMA.
// R13 = R12 + BAND-SWEPT pair stream: at q-step, block p reads 64-row group
// (gbase + q*2048 + p) -> concurrently-resident blocks read adjacent chunks
// within a 64MB band (copy-benchmark spatial pattern, DRAM row locality).
// ---------------------------------------------------------------------------

typedef __attribute__((ext_vector_type(8))) short bf16x8;
typedef __attribute__((ext_vector_type(4))) float f32x4;
typedef __attribute__((ext_vector_type(4))) unsigned short us4;

#define DEVFN static __device__ __forceinline__

DEVFN float bf2f(unsigned short u){
  union { unsigned int u; float f; } v; v.u = ((unsigned int)u) << 16; return v.f;
}
DEVFN unsigned short f2bf(float f){
  union { float f; unsigned int u; } v; v.f = f;
  unsigned int r = v.u + 0x7fffu + ((v.u >> 16) & 1u);
  return (unsigned short)(r >> 16);
}
DEVFN unsigned short f2bf_trunc(float f){
  union { float f; unsigned int u; } v; v.f = f;
  return (unsigned short)(v.u >> 16);
}
DEVFN float sigf(float x){ return 1.f / (1.f + __expf(-x)); }

DEVFN void gload16(const void* g, void* l){
  __builtin_amdgcn_global_load_lds(
      (const __attribute__((address_space(1))) void*)g,
      (__attribute__((address_space(3))) void*)l, 16, 0, 0);
}

// ---------------- workspace layout (bytes) ----------------
#define OFF_SN    0x0000000ULL
#define OFF_SC    0x0180000ULL
#define OFF_XA    0x0300000ULL
#define OFF_W1    0x0600000ULL
#define OFF_W2    0x0A80000ULL
#define OFF_W3    0x0CC0000ULL
#define OFF_W4    0x1140000ULL
#define OFF_W5    0x15C0000ULL
#define OFF_W6    0x1800000ULL
#define OFF_BIAS1 0x1920000ULL
#define OFF_BIASG 0x1923000ULL
#define OFF_BIASQ 0x1924800ULL
#define OFF_G1    0x1930000ULL
#define OFF_GATES 0x2530000ULL
#define OFF_A     0x2B30000ULL
#define OFF_F     0x2CB0000ULL
#define OFF_QH    0x2E30000ULL
#define OFF_KH    0x2FB0000ULL
#define OFF_GH    0x3130000ULL
#define OFF_VT    0x3430000ULL
#define OFF_HH    0x4030000ULL
#define OFF_GO    0x4330000ULL
#define OFF_PB    0x47B0000ULL

struct WJobs {
  const float* src[8];
  unsigned long long dst[8];
  int K[8];
  int N[8];
  int rowmul[8];
  int rowoff[8];
};

// ---------------- transpose tile: dst[n*rm+ro][k] = bf16(src[k][n]) --------
DEVFN void transpose_tile(const WJobs& jobs, char* ws, int t, int tid, void* smem){
  int z = 0;
  while(true){
    int nt = (jobs.N[z] >> 5) * (jobs.K[z] >> 5);
    if(t < nt) break;
    t -= nt; z++;
  }
  const int nx = jobs.N[z] >> 5;
  const int n0 = (t % nx) << 5, k0 = (t / nx) << 5;
  const int K = jobs.K[z], N = jobs.N[z];
  float (*tt)[33] = (float(*)[33])smem;
  const int tx = tid & 31, ty = tid >> 5;
  const float* src = jobs.src[z];
  #pragma unroll
  for(int i=0;i<4;i++)
    tt[ty + i*8][tx] = src[(long long)(k0 + ty + i*8) * N + n0 + tx];
  __syncthreads();
  unsigned short* dst = (unsigned short*)(ws + jobs.dst[z]);
  const int rm = jobs.rowmul[z], ro = jobs.rowoff[z];
  #pragma unroll
  for(int i=0;i<4;i++)
    dst[(long long)((n0 + ty + i*8)*rm + ro) * K + k0 + tx] = f2bf(tt[tx][ty + i*8]);
}

// ---------------- prep: W1/W2 transpose + LN rows + bias build -------------
__global__ __launch_bounds__(256) void prep_kernel(WJobs jobsP, char* ws,
    const float* __restrict__ x, const float* __restrict__ sc,
    unsigned short* __restrict__ sn_bf, unsigned short* __restrict__ sc_bf,
    float* __restrict__ xa,
    const float* agb, const float* bq, const float* gtb, const float* fgtb,
    const float* fgb, float* bias1, float* biasg, float* biasq){
  __shared__ __align__(16) char smem[4352];
  const int bid = blockIdx.x;
  const int tid = threadIdx.x;
  if(bid < 3456){
    transpose_tile(jobsP, ws, bid, tid, smem);
    return;
  }
  if(bid >= 4480){
    int t = (bid - 4480) * 256 + tid;
    float v = 0.f;
    if(t < 768) v = agb[t];
    else if(t >= 1536 && t < 2304) v = fgb[t - 1536];
    bias1[t] = v;
    biasq[t] = (t < 768) ? bq[t] : 0.f;
    if(t < 1536) biasg[t] = (t < 768) ? gtb[t] : fgtb[t - 768];
    return;
  }
  const int row = bid - 3456;
  const float* xr = x + (long long)row * 768;
  const float* sr = sc + (long long)row * 768;
  float xs[3], ss[3];
  float s0=0.f, s1=0.f, s2=0.f, s3=0.f;
  #pragma unroll
  for(int i=0;i<3;i++){
    float xv = xr[tid + i*256], sv = sr[tid + i*256];
    xs[i]=xv; ss[i]=sv;
    s0 += xv; s1 += xv*xv; s2 += sv; s3 += sv*sv;
  }
  #pragma unroll
  for(int o=32;o;o>>=1){
    s0 += __shfl_xor(s0,o); s1 += __shfl_xor(s1,o);
    s2 += __shfl_xor(s2,o); s3 += __shfl_xor(s3,o);
  }
  float (*red)[4] = (float(*)[4])smem;
  const int w = tid >> 6;
  if((tid & 63) == 0){ red[0][w]=s0; red[1][w]=s1; red[2][w]=s2; red[3][w]=s3; }
  __syncthreads();
  float tx0 = red[0][0]+red[0][1]+red[0][2]+red[0][3];
  float tx1 = red[1][0]+red[1][1]+red[1][2]+red[1][3];
  float ts0 = red[2][0]+red[2][1]+red[2][2]+red[2][3];
  float ts1 = red[3][0]+red[3][1]+red[3][2]+red[3][3];
  const float inv = 1.f/768.f;
  float mx = tx0*inv, vx = tx1*inv - mx*mx;
  float ms = ts0*inv, vs = ts1*inv - ms*ms;
  float rsx = rsqrtf(vx + 1e-5f), rss = rsqrtf(vs + 1e-5f);
  #pragma unroll
  for(int i=0;i<3;i++){
    int c = tid + i*256;
    xa[(long long)row*768 + c]    = (xs[i]-mx)*rsx;
    sn_bf[(long long)row*768 + c] = f2bf((ss[i]-ms)*rss);
    sc_bf[(long long)row*768 + c] = f2bf(ss[i]);
  }
}

// ---------------- shared GEMM tile body (128x128, BK=32, gload_lds) --------
DEVFN void gemm_tile_f32(const unsigned short* __restrict__ A,
                         const unsigned short* __restrict__ Bt,
                         int N, int K, int m0, int n0,
                         const float* __restrict__ bias,
                         float* __restrict__ Cf, int epi,
                         unsigned short* sA, unsigned short* sB, int tid){
  const int w = tid >> 6, l = tid & 63, l15 = l & 15, l4 = l >> 4;
  const int wm = w >> 1, wn = w & 1;
  f32x4 zf = {0.f,0.f,0.f,0.f};
  f32x4 acc[4][4];
  #pragma unroll
  for(int m=0;m<4;m++)
    #pragma unroll
    for(int n=0;n<4;n++) acc[m][n] = zf;

  const int srow = w*16 + (l >> 2);
  const int scol = (l & 3) * 8;
  const unsigned short* gA = A  + (long long)(m0 + srow) * K + scol;
  const unsigned short* gB = Bt + (long long)(n0 + srow) * K + scol;
  unsigned short* lA0 = &sA[(w*16)*32];
  unsigned short* lA1 = &sA[(64 + w*16)*32];
  unsigned short* lB0 = &sB[(w*16)*32];
  unsigned short* lB1 = &sB[(64 + w*16)*32];
  const long long half = (long long)64 * K;

  for(int k0 = 0; k0 < K; k0 += 32){
    gload16(gA + k0, lA0);
    gload16(gA + half + k0, lA1);
    gload16(gB + k0, lB0);
    gload16(gB + half + k0, lB1);
    __syncthreads();
    bf16x8 af[4], bg[4];
    #pragma unroll
    for(int m=0;m<4;m++) af[m] = *(const bf16x8*)&sA[(wm*64 + m*16 + l15)*32 + l4*8];
    #pragma unroll
    for(int n=0;n<4;n++) bg[n] = *(const bf16x8*)&sB[(wn*64 + n*16 + l15)*32 + l4*8];
    #pragma unroll
    for(int m=0;m<4;m++)
      #pragma unroll
      for(int n=0;n<4;n++)
        acc[m][n] = __builtin_amdgcn_mfma_f32_16x16x32_bf16(af[m], bg[n], acc[m][n], 0, 0, 0);
    __syncthreads();
  }
  #pragma unroll
  for(int m=0;m<4;m++){
    #pragma unroll
    for(int n=0;n<4;n++){
      #pragma unroll
      for(int r=0;r<4;r++){
        const int i = m0 + wm*64 + m*16 + l4*4 + r;
        const int c = n0 + wn*64 + n*16 + l15;
        float v = acc[m][n][r] + bias[c];
        Cf[(long long)i*N + c] = epi ? sigf(v) : v;
      }
    }
  }
}

// ---------------- pair-bias block: band-swept + wave-autonomous staging ----
// At step q, block p processes 64-row group (gbase + q*2048 + p): all resident
// blocks read adjacent 32KB chunks of a 64MB band sweeping forward together.
DEVFN void pair_block(int p, int gbase, const float* __restrict__ pair,
                      const float* __restrict__ wb,
                      unsigned short* __restrict__ pb, int tid, char* lds){
  const int l = tid & 63, w = tid >> 6, l15 = l & 15, l4 = l >> 4;
  bf16x8 wbf[4];
  #pragma unroll
  for(int c=0;c<4;c++){
    bf16x8 t;
    #pragma unroll
    for(int e=0;e<8;e++) t[e] = (short)f2bf(wb[(c*32 + l4*8 + e)*16 + l15]);
    wbf[c] = t;
  }
  char* wlds = lds + w*8192;
  const int lane16 = (l & 31) * 16;
  const int lhi = l >> 5;
  const int swr = l15 << 4;

  for(int q=0;q<4;q++){
    const long long grouprow = ((long long)(gbase + q*2048 + p)) << 6; // *64
    const char* gbptr = (const char*)pair + (grouprow << 9);
    #pragma unroll
    for(int is=0; is<8; is++){
      const int r = w*16 + is*2 + lhi;            // staged row 0..63
      gload16(gbptr + ((long long)r << 9) + (lane16 ^ ((r & 15) << 4)),
              wlds + is*1024);
    }
    asm volatile("s_waitcnt vmcnt(0)" ::: "memory");
    __builtin_amdgcn_sched_barrier(0);
    const char* rowp = wlds + l15*512;
    float vals[32];
    #pragma unroll
    for(int c=0;c<4;c++){
      const int x = c*128 + l4*32;
      float4 v0 = *(const float4*)(rowp + (x ^ swr));
      float4 v1 = *(const float4*)(rowp + ((x + 16) ^ swr));
      vals[c*8+0]=v0.x; vals[c*8+1]=v0.y; vals[c*8+2]=v0.z; vals[c*8+3]=v0.w;
      vals[c*8+4]=v1.x; vals[c*8+5]=v1.y; vals[c*8+6]=v1.z; vals[c*8+7]=v1.w;
    }
    float s=0.f, s2=0.f;
    #pragma unroll
    for(int e=0;e<32;e++){ s += vals[e]; s2 += vals[e]*vals[e]; }
    s += __shfl_xor(s, 16); s2 += __shfl_xor(s2, 16);
    s += __shfl_xor(s, 32); s2 += __shfl_xor(s2, 32);
    const float m = s * (1.f/128.f);
    const float rs = rsqrtf(s2*(1.f/128.f) - m*m + 1e-5f);
    f32x4 acc = {0.f,0.f,0.f,0.f};
    #pragma unroll
    for(int c=0;c<4;c++){
      bf16x8 af;
      #pragma unroll
      for(int e=0;e<8;e++) af[e] = (short)f2bf_trunc((vals[c*8+e] - m) * rs);
      acc = __builtin_amdgcn_mfma_f32_16x16x32_bf16(af, wbf[c], acc, 0,0,0);
    }
    const long long row0 = grouprow + w*16;
    us4 o;
    #pragma unroll
    for(int r=0;r<4;r++) o[r] = f2bf(acc[r]);
    *(us4*)&pb[((long long)l15 << 20) + row0 + l4*4] = o;
    asm volatile("s_waitcnt lgkmcnt(0)" ::: "memory");
    __builtin_amdgcn_sched_barrier(0);
  }
}

// ---------------- fA: G1+gates GEMMs + W3..W6 transposes + pair groups -----
// grid 8672: [0,288) GEMM, [288,6624) transpose, [6624,8672) pair gbase=0.
__global__ __launch_bounds__(256) void fA_kernel(
    WJobs jobsA, char* ws,
    const float* __restrict__ pair, const float* __restrict__ wb,
    unsigned short* __restrict__ pb,
    const unsigned short* __restrict__ SN, const unsigned short* __restrict__ W1,
    const float* __restrict__ B1, float* __restrict__ G1,
    const unsigned short* __restrict__ SC, const unsigned short* __restrict__ W2,
    const float* __restrict__ BG, float* __restrict__ GT){
  __shared__ __align__(16) unsigned short smem[16384];   // 32 KB
  const int bid = blockIdx.x;
  const int tid = threadIdx.x;
  if(bid < 288){
    if(bid < 192){
      gemm_tile_f32(SN, W1, 3072, 768, (bid & 7)*128, (bid >> 3)*128, B1, G1, 0,
                    smem, smem + 4096, tid);
    } else {
      const int t = bid - 192;
      gemm_tile_f32(SC, W2, 1536, 768, (t & 7)*128, (t >> 3)*128, BG, GT, 1,
                    smem, smem + 4096, tid);
    }
    return;
  }
  if(bid < 6624){
    transpose_tile(jobsA, ws, bid - 288, tid, smem);
    return;
  }
  pair_block(bid - 6624, 0, pair, wb, pb, tid, (char*)smem);
}

// ---------------- elementwise: adaLN combine + out=x init ----------------
__global__ __launch_bounds__(256) void ew1_kernel(const float* __restrict__ g1,
    const float* __restrict__ xa, unsigned short* __restrict__ a_bf,
    unsigned short* __restrict__ f_bf, const float* __restrict__ x,
    float* __restrict__ out){
  const int i = blockIdx.x;
  const int c = blockIdx.y * 256 + threadIdx.x;
  const float* row = g1 + (long long)i * 3072;
  float xv = xa[(long long)i*768 + c];
  a_bf[(long long)i*768 + c] = f2bf(sigf(row[c])      * xv + row[768 + c]);
  f_bf[(long long)i*768 + c] = f2bf(sigf(row[1536+c]) * xv + row[2304 + c]);
  out[(long long)i*768 + c] = x[(long long)i*768 + c];
}

// ---------------- fB: QKVG GEMM (head-major out) + HH GEMM + pair ----------
__global__ __launch_bounds__(256) void fB_kernel(
    const float* __restrict__ pair, const float* __restrict__ wb,
    unsigned short* __restrict__ pb,
    const unsigned short* __restrict__ A_, const unsigned short* __restrict__ W3,
    const float* __restrict__ BQ,
    unsigned short* __restrict__ QH, unsigned short* __restrict__ KH,
    unsigned short* __restrict__ GH, unsigned short* __restrict__ VT,
    const unsigned short* __restrict__ F_, const unsigned short* __restrict__ W4,
    unsigned short* __restrict__ HH){
  __shared__ __align__(16) unsigned short smem[16384];   // 32 KB
  const int bid = blockIdx.x;
  const int tid = threadIdx.x;
  if(bid >= 384){
    pair_block(bid - 384, 8192, pair, wb, pb, tid, (char*)smem);
    return;
  }
  unsigned short* sA = smem;
  unsigned short* sB = smem + 4096;
  const bool isq = bid < 192;
  const int t = isq ? bid : bid - 192;
  const int m0 = (t & 7) * 128, n0 = (t >> 3) * 128;
  const unsigned short* A  = isq ? A_ : F_;
  const unsigned short* Bt = isq ? W3 : W4;
  const int K = 768;

  const int w = tid >> 6, l = tid & 63, l15 = l & 15, l4 = l >> 4;
  const int wm = w >> 1, wn = w & 1;
  f32x4 zf = {0.f,0.f,0.f,0.f};
  f32x4 acc[4][4];
  #pragma unroll
  for(int m=0;m<4;m++)
    #pragma unroll
    for(int n=0;n<4;n++) acc[m][n] = zf;

  const int srow = w*16 + (l >> 2);
  const int scol = (l & 3) * 8;
  const unsigned short* gA = A  + (long long)(m0 + srow) * K + scol;
  const unsigned short* gB = Bt + (long long)(n0 + srow) * K + scol;
  unsigned short* lA0 = &sA[(w*16)*32];
  unsigned short* lA1 = &sA[(64 + w*16)*32];
  unsigned short* lB0 = &sB[(w*16)*32];
  unsigned short* lB1 = &sB[(64 + w*16)*32];
  const long long half = (long long)64 * K;

  for(int k0 = 0; k0 < K; k0 += 32){
    gload16(gA + k0, lA0);
    gload16(gA + half + k0, lA1);
    gload16(gB + k0, lB0);
    gload16(gB + half + k0, lB1);
    __syncthreads();
    bf16x8 af[4], bg[4];
    #pragma unroll
    for(int m=0;m<4;m++) af[m] = *(const bf16x8*)&sA[(wm*64 + m*16 + l15)*32 + l4*8];
    #pragma unroll
    for(int n=0;n<4;n++) bg[n] = *(const bf16x8*)&sB[(wn*64 + n*16 + l15)*32 + l4*8];
    #pragma unroll
    for(int m=0;m<4;m++)
      #pragma unroll
      for(int n=0;n<4;n++)
        acc[m][n] = __builtin_amdgcn_mfma_f32_16x16x32_bf16(af[m], bg[n], acc[m][n], 0, 0, 0);
    __syncthreads();
  }
  if(isq){
    #pragma unroll
    for(int m=0;m<4;m++){
      #pragma unroll
      for(int n=0;n<4;n++){
        const int c = n0 + wn*64 + n*16 + l15;
        const int ibase = m0 + wm*64 + m*16 + l4*4;
        const int which = c / 768;           // 0=q 1=k 2=v 3=g
        const int h = (c % 768) / 48, d = c % 48;
        unsigned short vb[4];
        #pragma unroll
        for(int r=0;r<4;r++) vb[r] = f2bf(acc[m][n][r] + BQ[c]);
        if(which == 2){
          us4 o; o.x=vb[0]; o.y=vb[1]; o.z=vb[2]; o.w=vb[3];
          *(us4*)&VT[((long long)(c - 1536) << 10) + ibase] = o;
        } else {
          unsigned short* dst = (which == 0) ? QH : (which == 1) ? KH : GH;
          #pragma unroll
          for(int r=0;r<4;r++)
            dst[((long long)((h << 10) + ibase + r))*48 + d] = vb[r];
        }
      }
    }
  } else {
    #pragma unroll
    for(int m=0;m<4;m++){
      #pragma unroll
      for(int n=0;n<4;n++){
        #pragma unroll
        for(int r=0;r<4;r++){
          const int i = m0 + wm*64 + m*16 + l4*4 + r;
          const int c = n0 + wn*64 + n*16 + l15;
          float v = acc[m][n][r];
          float partner = __shfl_xor(v, 1);
          if((c & 1) == 0)
            HH[(long long)i*1536 + (c>>1)] = f2bf(v * sigf(v) * partner);
        }
      }
    }
  }
}

// ---------------- final GEMM-slice body (split-K atomics into out) ---------
DEVFN void final_slice(const unsigned short* __restrict__ A,
                       const unsigned short* __restrict__ Bt,
                       int K, int kbeg, int kend, int goff, int m0, int n0,
                       const float* __restrict__ gates, float* __restrict__ out,
                       unsigned short* sA, unsigned short* sB, int tid){
  const int w = tid >> 6, l = tid & 63, l15 = l & 15, l4 = l >> 4;
  const int wm = w >> 1, wn = w & 1;
  f32x4 zf = {0.f,0.f,0.f,0.f};
  f32x4 acc[4][4];
  #pragma unroll
  for(int m=0;m<4;m++)
    #pragma unroll
    for(int n=0;n<4;n++) acc[m][n] = zf;

  const int srow = w*16 + (l >> 2);
  const int scol = (l & 3) * 8;
  const unsigned short* gA = A  + (long long)(m0 + srow) * K + scol;
  const unsigned short* gB = Bt + (long long)(n0 + srow) * K + scol;
  unsigned short* lA0 = &sA[(w*16)*32];
  unsigned short* lA1 = &sA[(64 + w*16)*32];
  unsigned short* lB0 = &sB[(w*16)*32];
  unsigned short* lB1 = &sB[(64 + w*16)*32];
  const long long half = (long long)64 * K;

  for(int k0 = kbeg; k0 < kend; k0 += 32){
    gload16(gA + k0, lA0);
    gload16(gA + half + k0, lA1);
    gload16(gB + k0, lB0);
    gload16(gB + half + k0, lB1);
    __syncthreads();
    bf16x8 af[4], bg[4];
    #pragma unroll
    for(int m=0;m<4;m++) af[m] = *(const bf16x8*)&sA[(wm*64 + m*16 + l15)*32 + l4*8];
    #pragma unroll
    for(int n=0;n<4;n++) bg[n] = *(const bf16x8*)&sB[(wn*64 + n*16 + l15)*32 + l4*8];
    #pragma unroll
    for(int m=0;m<4;m++)
      #pragma unroll
      for(int n=0;n<4;n++)
        acc[m][n] = __builtin_amdgcn_mfma_f32_16x16x32_bf16(af[m], bg[n], acc[m][n], 0, 0, 0);
    __syncthreads();
  }
  #pragma unroll
  for(int m=0;m<4;m++){
    #pragma unroll
    for(int n=0;n<4;n++){
      #pragma unroll
      for(int r=0;r<4;r++){
        const int i = m0 + wm*64 + m*16 + l4*4 + r;
        const int c = n0 + wn*64 + n*16 + l15;
        float v = gates[(long long)i*1536 + goff + c] * acc[m][n][r];
        __hip_atomic_fetch_add(&out[(long long)i*768 + c], v,
                               __ATOMIC_RELAXED, __HIP_MEMORY_SCOPE_AGENT);
      }
    }
  }
}

// ---------------- attn launch: [0,192) finalB (HH@W5) + [192,1216) attn ----
__global__ __launch_bounds__(256) void attn_kernel(
    const unsigned short* __restrict__ QH, const unsigned short* __restrict__ KH,
    const unsigned short* __restrict__ GH,
    const unsigned short* __restrict__ pbias,
    const unsigned short* __restrict__ VT,
    unsigned short* __restrict__ go,
    const unsigned short* __restrict__ HH, const unsigned short* __restrict__ W5t,
    const float* __restrict__ gates, float* __restrict__ out){
  __shared__ __align__(16) char smem[45824];
  const int bid = blockIdx.x;
  const int tid = threadIdx.x;
  if(bid < 192){
    const int z = bid / 48, rem = bid % 48;
    final_slice(HH, W5t, 1536, z*384, z*384 + 384, 768,
                (rem & 7)*128, (rem >> 3)*128, gates, out,
                (unsigned short*)smem, (unsigned short*)(smem + 8192), tid);
    return;
  }
  const int it = bid - 192;
  const int h  = it >> 6;
  const int i0 = (it & 63) << 4;
  const int w = tid >> 6, l = tid & 63, l15 = l & 15, l4 = l >> 4;

  unsigned short (*sP)[1032] = (unsigned short(*)[1032])smem;      // 33024
  float (*sRedM)[4] = (float(*)[4])(smem + 33024);                 // 256
  float (*sRedS)[4] = (float(*)[4])(smem + 33280);                 // 256
  float (*sO)[16][48] = (float(*)[16][48])(smem + 33536);          // 12288

  f32x4 zf = {0.f,0.f,0.f,0.f};
  bf16x8 zero8 = {0,0,0,0,0,0,0,0};

  const unsigned short* pbh = pbias + ((long long)h << 20) + ((long long)i0 << 10);
  #pragma unroll
  for(int itr=0; itr<8; itr++){
    const int idx = itr*2048 + tid*8;
    const int r = idx >> 10, c = idx & 1023;
    *(bf16x8*)&sP[r][c] = *(const bf16x8*)&pbh[((long long)r << 10) + c];
  }

  // ---- QK^T ----
  f32x4 accs[16];
  #pragma unroll
  for(int f=0;f<16;f++) accs[f] = zf;
  bf16x8 aq0, aq1;
  {
    const unsigned short* qp = QH + (long long)((h << 10) + i0 + l15)*48;
    aq0 = *(const bf16x8*)(qp + l4*8);
    aq1 = *(const bf16x8*)(qp + 32 + l4*8);
  }
  const int jbase = w * 256;
  #pragma unroll
  for(int f=0; f<16; f++){
    const int j = jbase + f*16 + l15;
    const unsigned short* kp = KH + (long long)((h << 10) + j)*48;
    bf16x8 bk0 = *(const bf16x8*)(kp + l4*8);
    bf16x8 bk1 = *(const bf16x8*)(kp + 32 + l4*8);
    if(l4 >= 2) bk1 = zero8;
    accs[f] = __builtin_amdgcn_mfma_f32_16x16x32_bf16(aq0, bk0, accs[f], 0,0,0);
    accs[f] = __builtin_amdgcn_mfma_f32_16x16x32_bf16(aq1, bk1, accs[f], 0,0,0);
  }
  __syncthreads();   // sP bias staged

  const float scale = 0.14433756729740643f;  // 1/sqrt(48)
  #pragma unroll
  for(int f=0;f<16;f++){
    #pragma unroll
    for(int r=0;r<4;r++)
      accs[f][r] = accs[f][r]*scale + bf2f(sP[l4*4 + r][jbase + f*16 + l15]);
  }
  // ---- softmax (unnormalized) ----
  float pm[4];
  #pragma unroll
  for(int r=0;r<4;r++){
    float m = accs[0][r];
    #pragma unroll
    for(int f=1;f<16;f++) m = fmaxf(m, accs[f][r]);
    #pragma unroll
    for(int o=1;o<16;o<<=1) m = fmaxf(m, __shfl_xor(m, o));
    pm[r] = m;
  }
  if(l15 == 0){
    #pragma unroll
    for(int r=0;r<4;r++) sRedM[l4*4 + r][w] = pm[r];
  }
  __syncthreads();
  float rowm[4];
  #pragma unroll
  for(int r=0;r<4;r++){
    const int i = l4*4 + r;
    rowm[r] = fmaxf(fmaxf(sRedM[i][0], sRedM[i][1]), fmaxf(sRedM[i][2], sRedM[i][3]));
  }
  float psum[4] = {0.f,0.f,0.f,0.f};
  #pragma unroll
  for(int f=0;f<16;f++)
    #pragma unroll
    for(int r=0;r<4;r++){
      float p = __expf(accs[f][r] - rowm[r]);
      accs[f][r] = p;
      psum[r] += p;
    }
  #pragma unroll
  for(int r=0;r<4;r++)
    #pragma unroll
    for(int o=1;o<16;o<<=1) psum[r] += __shfl_xor(psum[r], o);
  if(l15 == 0){
    #pragma unroll
    for(int r=0;r<4;r++) sRedS[l4*4 + r][w] = psum[r];
  }
  #pragma unroll
  for(int f=0;f<16;f++)
    #pragma unroll
    for(int r=0;r<4;r++)
      sP[l4*4 + r][jbase + f*16 + l15] = f2bf(accs[f][r]);

  // ---- PV: B-frags straight from global VT (L2-hot) ----
  f32x4 acco[3];
  #pragma unroll
  for(int n=0;n<3;n++) acco[n] = zf;
  const unsigned short* vth = VT + ((long long)(h*48) << 10);
  #pragma unroll
  for(int c=0; c<4; c++){
    const int jb = jbase + c*64;
    #pragma unroll
    for(int kk=0; kk<2; kk++){
      bf16x8 pa = *(const bf16x8*)&sP[l15][jb + kk*32 + l4*8];
      #pragma unroll
      for(int n=0;n<3;n++){
        bf16x8 bv = *(const bf16x8*)&vth[((long long)(n*16 + l15) << 10) + jb + kk*32 + l4*8];
        acco[n] = __builtin_amdgcn_mfma_f32_16x16x32_bf16(pa, bv, acco[n], 0,0,0);
      }
    }
  }
  #pragma unroll
  for(int n=0;n<3;n++)
    #pragma unroll
    for(int r=0;r<4;r++)
      sO[w][l4*4 + r][n*16 + l15] = acco[n][r];
  __syncthreads();
  for(int t = tid; t < 768; t += 256){
    const int i = t / 48, d = t % 48;
    float o = sO[0][i][d] + sO[1][i][d] + sO[2][i][d] + sO[3][i][d];
    float lsum = sRedS[i][0] + sRedS[i][1] + sRedS[i][2] + sRedS[i][3];
    float gv = bf2f(GH[(long long)((h << 10) + i0 + i)*48 + d]);
    go[(long long)(i0 + i)*768 + h*48 + d] = f2bf(sigf(gv) * (o / lsum));
  }
}

// ---------------- finalA: out += gateA*(GO@W6), 4-way split-K -------------
__global__ __launch_bounds__(256) void finalA_kernel(
    const unsigned short* __restrict__ GO, const unsigned short* __restrict__ W6t,
    const float* __restrict__ gates, float* __restrict__ out){
  __shared__ __align__(16) unsigned short sA[128*32];
  __shared__ __align__(16) unsigned short sB[128*32];
  final_slice(GO, W6t, 768, blockIdx.z*192, blockIdx.z*192 + 192, 0,
              blockIdx.x*128, blockIdx.y*128, gates, out, sA, sB, threadIdx.x);
}

// ---------------------------------------------------------------------------
extern "C" void kernel_launch(void* const* d_in, const int* in_sizes, int n_in,
                              void* d_out, int out_size, void* d_ws, size_t ws_size,
                              hipStream_t stream){
  (void)in_sizes; (void)n_in; (void)out_size; (void)ws_size;
  const float* x    = (const float*)d_in[0];
  const float* sc   = (const float*)d_in[1];
  const float* pair = (const float*)d_in[2];
  const float* agw  = (const float*)d_in[3];
  const float* agb  = (const float*)d_in[4];
  const float* abw  = (const float*)d_in[5];
  const float* wq   = (const float*)d_in[6];
  const float* bq   = (const float*)d_in[7];
  const float* wk   = (const float*)d_in[8];
  const float* wv   = (const float*)d_in[9];
  const float* wb   = (const float*)d_in[10];
  const float* wg   = (const float*)d_in[11];
  const float* wo   = (const float*)d_in[12];
  const float* gtw  = (const float*)d_in[13];
  const float* gtb  = (const float*)d_in[14];
  const float* fgw  = (const float*)d_in[15];
  const float* fgb  = (const float*)d_in[16];
  const float* fbw  = (const float*)d_in[17];
  const float* fw1  = (const float*)d_in[18];
  const float* fw2  = (const float*)d_in[19];
  const float* fw3  = (const float*)d_in[20];
  const float* fgtw = (const float*)d_in[21];
  const float* fgtb = (const float*)d_in[22];
  float* out = (float*)d_out;
  char* ws = (char*)d_ws;

  unsigned short* SN   = (unsigned short*)(ws + OFF_SN);
  unsigned short* SC   = (unsigned short*)(ws + OFF_SC);
  float*          XA   = (float*)(ws + OFF_XA);
  unsigned short* W1   = (unsigned short*)(ws + OFF_W1);
  unsigned short* W2   = (unsigned short*)(ws + OFF_W2);
  unsigned short* W3   = (unsigned short*)(ws + OFF_W3);
  unsigned short* W4   = (unsigned short*)(ws + OFF_W4);
  unsigned short* W5   = (unsigned short*)(ws + OFF_W5);
  unsigned short* W6   = (unsigned short*)(ws + OFF_W6);
  float*          B1   = (float*)(ws + OFF_BIAS1);
  float*          BG   = (float*)(ws + OFF_BIASG);
  float*          BQ   = (float*)(ws + OFF_BIASQ);
  float*          G1   = (float*)(ws + OFF_G1);
  float*          GT   = (float*)(ws + OFF_GATES);
  unsigned short* A_   = (unsigned short*)(ws + OFF_A);
  unsigned short* F_   = (unsigned short*)(ws + OFF_F);
  unsigned short* QH   = (unsigned short*)(ws + OFF_QH);
  unsigned short* KH   = (unsigned short*)(ws + OFF_KH);
  unsigned short* GH   = (unsigned short*)(ws + OFF_GH);
  unsigned short* VT   = (unsigned short*)(ws + OFF_VT);
  unsigned short* HH   = (unsigned short*)(ws + OFF_HH);
  unsigned short* GO   = (unsigned short*)(ws + OFF_GO);
  unsigned short* PB   = (unsigned short*)(ws + OFF_PB);

  const unsigned long long W768 = 768ULL*768ULL*2ULL;

  WJobs jobsP;
  {
    int ji = 0;
    auto setj = [&](const float* s, unsigned long long off, int K, int N,
                    int rm, int ro){
      jobsP.src[ji]=s; jobsP.dst[ji]=off; jobsP.K[ji]=K; jobsP.N[ji]=N;
      jobsP.rowmul[ji]=rm; jobsP.rowoff[ji]=ro; ji++;
    };
    setj(agw,  OFF_W1 + 0*W768, 768, 768, 1, 0);
    setj(abw,  OFF_W1 + 1*W768, 768, 768, 1, 0);
    setj(fgw,  OFF_W1 + 2*W768, 768, 768, 1, 0);
    setj(fbw,  OFF_W1 + 3*W768, 768, 768, 1, 0);
    setj(gtw,  OFF_W2 + 0*W768, 768, 768, 1, 0);
    setj(fgtw, OFF_W2 + 1*W768, 768, 768, 1, 0);
  }
  WJobs jobsA;
  {
    int ji = 0;
    auto setj = [&](const float* s, unsigned long long off, int K, int N,
                    int rm, int ro){
      jobsA.src[ji]=s; jobsA.dst[ji]=off; jobsA.K[ji]=K; jobsA.N[ji]=N;
      jobsA.rowmul[ji]=rm; jobsA.rowoff[ji]=ro; ji++;
    };
    setj(wq,   OFF_W3 + 0*W768, 768, 768, 1, 0);
    setj(wk,   OFF_W3 + 1*W768, 768, 768, 1, 0);
    setj(wv,   OFF_W3 + 2*W768, 768, 768, 1, 0);
    setj(wg,   OFF_W3 + 3*W768, 768, 768, 1, 0);
    setj(fw1,  OFF_W4, 768, 1536, 2, 0);
    setj(fw2,  OFF_W4, 768, 1536, 2, 1);
    setj(fw3,  OFF_W5, 1536, 768, 1, 0);
    setj(wo,   OFF_W6, 768, 768, 1, 0);
  }

  prep_kernel<<<4492, 256, 0, stream>>>(jobsP, ws, x, sc, SN, SC, XA,
      agb, bq, gtb, fgtb, fgb, B1, BG, BQ);
  fA_kernel<<<8672, 256, 0, stream>>>(jobsA, ws, pair, wb, PB,
      SN, W1, B1, G1, SC, W2, BG, GT);
  ew1_kernel<<<dim3(1024,3), 256, 0, stream>>>(G1, XA, A_, F_, x, out);
  fB_kernel<<<2432, 256, 0, stream>>>(pair, wb, PB, A_, W3, BQ,
      QH, KH, GH, VT, F_, W4, HH);
  attn_kernel<<<1216, 256, 0, stream>>>(QH, KH, GH, PB, VT, GO,
      HH, W5, GT, out);
  finalA_kernel<<<dim3(8,6,4), 256, 0, stream>>>(GO, W6, GT, out);
}